// Round 1
// baseline (183.595 us; speedup 1.0000x reference)
//
#include <hip/hip_runtime.h>

// B=4, Sx=Sy=512, H=128, D=2H=256, fp32.
// e1 = exp2(2log2e * x@W1^T)  (stored PRE-SWIZZLED: [b][c][hq][s^hq] float4)
// e2 = exp2(2log2e * y@W2^T)  (linear)
// tanh(s1+s2) = 1 - 2/(e1*e2+1); score = sum_h vc[h]*tanh(.)
// constant sum_h vc[h] dropped (softmax shift-invariant); -2 folded into the
// softmax read. P = softmax_s(score); out = P @ x.
// Quad-rcp: v1/f1+..+v4/f4 = (n12*f34+n34*f12)/(f12*f34), one rcp per 4 h.
//
// R5-R7: global_load_lds DMA for e1 (zero staging VGPRs), e1 pre-swizzled.
// R8: harness 256 MiB d_ws fill = ~40 us of every timed iteration (fixed tax).
// R9: pax rewrite (1 b128 global + 2 b128 LDS per 32 FMAs).
// R10: score t=4/block (512 blk x 1024 thr).
// R11: (a) score waves = 16 h-groups, each wave does ALL 4 t per e1 read ->
//      hot-loop ds_read_b128 / 4; cross-wave reduce via LDS atomicAdd
//      (ds_add_f32), sPartC deleted, LDS 72 KB -> still 2 blocks/CU.
//      (b) A1+A2 fused: part buffer (8 MB traffic) + 1 launch eliminated.
//      (c) pax 512 thr (8 waves/CU instead of 4) for L2-latency hiding.

#define NB 4
#define SEQ 512
#define HDIM 128
#define DDIM 256

static constexpr float TWO_LOG2E = 2.8853900817779268f; // 2*log2(e)
static constexpr float LOG2E     = 1.4426950408889634f;

__device__ __forceinline__ void gload_lds16(const void* g, void* l) {
    __builtin_amdgcn_global_load_lds(
        (const __attribute__((address_space(1))) void*)g,
        (__attribute__((address_space(3))) void*)l, 16, 0, 0);
}

// ---------------- Kernel A: fused projection + exp2 -----------------------
// 512 blocks x 256 thr. Block = 8 rows of x (gr0<2048) or y, full K=256.
// Epilogue applies exp2 and writes e1 swizzled / e2 linear directly.
__global__ __launch_bounds__(256) void proj_kernel(
    const float* __restrict__ x, const float* __restrict__ y,
    const float* __restrict__ W1, const float* __restrict__ W2,
    float* __restrict__ e1sw, float* __restrict__ e2)
{
    __shared__ float As[2048];      // [8 r][256 k]
    __shared__ float sPr[8192];     // [8 ks][8 r][128 h]
    const int tid = threadIdx.x;
    const int gr0 = blockIdx.x * 8;       // global virtual row base [0,4096)

    const float* in; const float* W; int srow;
    if (gr0 < 2048) { in = x; W = W1; srow = gr0; }
    else            { in = y; W = W2; srow = gr0 - 2048; }

    #pragma unroll
    for (int j = 0; j < 2; ++j) {
        const int idx = tid + j * 256;        // float4 slot [0,512)
        const int r = idx >> 6, kk = idx & 63;
        *(float4*)&As[idx * 4] =
            *(const float4*)&in[(srow + r) * 256 + kk * 4];
    }
    __syncthreads();

    const int hq = tid & 31;   // h-quad
    const int ks = tid >> 5;   // k-slice of 32

    float4 acc4[8];
    #pragma unroll
    for (int r = 0; r < 8; ++r) acc4[r] = make_float4(0.f, 0.f, 0.f, 0.f);

    #pragma unroll
    for (int u = 0; u < 8; ++u) {
        const int kof = ks * 32 + u * 4;
        const float4 w0 = *(const float4*)&W[(4*hq + 0) * 256 + kof];
        const float4 w1 = *(const float4*)&W[(4*hq + 1) * 256 + kof];
        const float4 w2 = *(const float4*)&W[(4*hq + 2) * 256 + kof];
        const float4 w3 = *(const float4*)&W[(4*hq + 3) * 256 + kof];
        #pragma unroll
        for (int r = 0; r < 8; ++r) {
            const float4 a = *(const float4*)&As[r * 256 + kof];
            acc4[r].x = fmaf(a.w,w0.w, fmaf(a.z,w0.z, fmaf(a.y,w0.y, fmaf(a.x,w0.x, acc4[r].x))));
            acc4[r].y = fmaf(a.w,w1.w, fmaf(a.z,w1.z, fmaf(a.y,w1.y, fmaf(a.x,w1.x, acc4[r].y))));
            acc4[r].z = fmaf(a.w,w2.w, fmaf(a.z,w2.z, fmaf(a.y,w2.y, fmaf(a.x,w2.x, acc4[r].z))));
            acc4[r].w = fmaf(a.w,w3.w, fmaf(a.z,w3.z, fmaf(a.y,w3.y, fmaf(a.x,w3.x, acc4[r].w))));
        }
    }
    #pragma unroll
    for (int r = 0; r < 8; ++r)
        *(float4*)&sPr[ks * 1024 + r * 128 + hq * 4] = acc4[r];
    __syncthreads();
    {
        const int r = tid >> 5, h4 = tid & 31;
        float4 s = make_float4(0.f, 0.f, 0.f, 0.f);
        #pragma unroll
        for (int k2 = 0; k2 < 8; ++k2) {
            const float4 p = *(const float4*)&sPr[k2 * 1024 + r * 128 + h4 * 4];
            s.x += p.x; s.y += p.y; s.z += p.z; s.w += p.w;
        }
        float4 o;
        o.x = __builtin_amdgcn_exp2f(s.x * TWO_LOG2E);
        o.y = __builtin_amdgcn_exp2f(s.y * TWO_LOG2E);
        o.z = __builtin_amdgcn_exp2f(s.z * TWO_LOG2E);
        o.w = __builtin_amdgcn_exp2f(s.w * TWO_LOG2E);
        const int gr = gr0 + r;
        if (gr < 2048) {
            const int b = gr >> 9, ss = gr & 511;
            const int c = ss >> 6, sl = ss & 63;
            ((float4*)e1sw)[((b * 8 + c) * 32 + h4) * 64 + (sl ^ h4)] = o;
        } else {
            ((float4*)e2)[(gr - 2048) * 32 + h4] = o;
        }
    }
}

// ---------------- Kernel B: scores + softmax -> P --------------------------
// 512 blocks x 1024 thr (16 waves). Block = (b, 4 t). Wave w = h-group of
// 8 h (quads 2w, 2w+1); each wave computes ALL 4 t per e1 LDS read (e1
// reuse x4 vs R10). e2/vc in SGPRs (uniform addrs via readfirstlane).
// e1 staged via global_load_lds DMA, double-buffered. Cross-wave partial
// reduce via LDS atomicAdd (native ds_add_f32); -2 folded into softmax
// read. LDS = 72 KB -> 2 blocks/CU = 32 waves/CU.
__global__ __launch_bounds__(1024) void score_kernel(
    const float* __restrict__ e1sw, const float* __restrict__ e2g,
    const float* __restrict__ vc,  float* __restrict__ P)
{
    __shared__ float4 sE1[2][2048];     // 2 x 32 KB
    __shared__ float  sScore[4 * 512];  // 8 KB

    const int tid  = threadIdx.x;
    const int b    = blockIdx.x >> 7;
    const int t0   = (blockIdx.x & 127) * 4;
    const int w    = tid >> 6;
    const int lane = tid & 63;
    const int wu   = __builtin_amdgcn_readfirstlane(w);
    const int hg   = wu;               // h-group: quads 2hg, 2hg+1

    // scalar operands: 2 vc quads + 4t x 2 e2 quads -> SGPRs
    float4 vcs[2];
    float4 e2s[4][2];
    #pragma unroll
    for (int j = 0; j < 2; ++j)
        vcs[j] = *(const float4*)&vc[(hg * 2 + j) * 4];
    #pragma unroll
    for (int t = 0; t < 4; ++t)
        #pragma unroll
        for (int j = 0; j < 2; ++j)
            e2s[t][j] = *(const float4*)&e2g[(b * SEQ + t0 + t) * HDIM + (hg * 2 + j) * 4];

    // zero the score accumulator (visible after first barrier)
    sScore[tid] = 0.f;
    sScore[tid + 1024] = 0.f;

    const float4* e1c = (const float4*)e1sw + b * 16384;  // 8 chunks x 2048

    // issue chunk 0 DMA into buf 0 (2 x 1KB segments per wave)
    #pragma unroll
    for (int j = 0; j < 2; ++j) {
        const int seg = wu * 128 + j * 64;
        gload_lds16(e1c + seg + lane, &sE1[0][seg]);
    }

    for (int c = 0; c < 8; ++c) {
        __syncthreads();   // drains DMA: buf[c&1] ready; zeros/adds visible
        if (c < 7) {
            const float4* gch = e1c + (c + 1) * 2048;
            #pragma unroll
            for (int j = 0; j < 2; ++j) {
                const int seg = wu * 128 + j * 64;
                gload_lds16(gch + seg + lane, &sE1[(c + 1) & 1][seg]);
            }
        }
        float acc0 = 0.f, acc1 = 0.f, acc2 = 0.f, acc3 = 0.f;
        const float4* buf = sE1[c & 1];
        #pragma unroll
        for (int j = 0; j < 2; ++j) {
            const int hq = hg * 2 + j;
            const float4 e1 = buf[hq * 64 + (lane ^ hq)];
            const float4 vv = vcs[j];
            #pragma unroll
            for (int t = 0; t < 4; ++t) {
                const float4 e2 = e2s[t][j];
                const float f1 = fmaf(e1.x, e2.x, 1.f);
                const float f2 = fmaf(e1.y, e2.y, 1.f);
                const float f3 = fmaf(e1.z, e2.z, 1.f);
                const float f4 = fmaf(e1.w, e2.w, 1.f);
                const float f12 = f1 * f2, f34 = f3 * f4;
                const float n12 = fmaf(vv.x, f2, vv.y * f1);
                const float n34 = fmaf(vv.z, f4, vv.w * f3);
                const float num = fmaf(n12, f34, n34 * f12);
                const float r = fmaf(num, __builtin_amdgcn_rcpf(f12 * f34),
                                     (t == 0) ? acc0 : (t == 1) ? acc1 : (t == 2) ? acc2 : acc3);
                if      (t == 0) acc0 = r;
                else if (t == 1) acc1 = r;
                else if (t == 2) acc2 = r;
                else             acc3 = r;
            }
        }
        atomicAdd(&sScore[0 * 512 + c * 64 + lane], acc0);
        atomicAdd(&sScore[1 * 512 + c * 64 + lane], acc1);
        atomicAdd(&sScore[2 * 512 + c * 64 + lane], acc2);
        atomicAdd(&sScore[3 * 512 + c * 64 + lane], acc3);
    }
    __syncthreads();

    // softmax: waves 0..3 -> t0+w; -2 scale applied here; write normalized P
    if (w < 4) {
        float v[8];
        float m = -1e30f;
        #pragma unroll
        for (int j = 0; j < 8; ++j) {
            v[j] = -2.f * sScore[w * 512 + lane + j * 64];
            m = fmaxf(m, v[j]);
        }
        #pragma unroll
        for (int off = 32; off; off >>= 1) m = fmaxf(m, __shfl_xor(m, off));
        float sum = 0.f;
        #pragma unroll
        for (int j = 0; j < 8; ++j) {
            v[j] = __builtin_amdgcn_exp2f((v[j] - m) * LOG2E);
            sum += v[j];
        }
        #pragma unroll
        for (int off = 32; off; off >>= 1) sum += __shfl_xor(sum, off);
        const float inv = __builtin_amdgcn_rcpf(sum);
        float* Prow = &P[(b * SEQ + t0 + w) * SEQ];
        #pragma unroll
        for (int j = 0; j < 8; ++j)
            Prow[lane + j * 64] = v[j] * inv;
    }
}

// ---------------- Kernel C: out = P @ x ------------------------------------
// R11: 256 blocks x 512 thr (8 waves, 2/SIMD). Wave w covers s in
// [64w, 64w+64); 8-way sRed reduce. LDS 80 KB.
__global__ __launch_bounds__(512) void pax_kernel(
    const float* __restrict__ P, const float* __restrict__ x,
    float* __restrict__ out)
{
    __shared__ float sP[SEQ * 8];        // 16 KB: [s][t]
    __shared__ float sRed[8 * 8 * DDIM]; // 64 KB: [w][t][d]
    const int tid = threadIdx.x;
    const int b   = blockIdx.x >> 6;
    const int t0  = (blockIdx.x & 63) * 8;
    const int w    = tid >> 6;
    const int lane = tid & 63;

    #pragma unroll
    for (int j = 0; j < 2; ++j) {
        const int i = tid + j * 512;          // [0,1024): t = i>>7, c4 = i&127
        const int t = i >> 7, c4 = i & 127;
        const float4 p = *(const float4*)&P[(b * SEQ + t0 + t) * SEQ + c4 * 4];
        sP[(c4 * 4 + 0) * 8 + t] = p.x;
        sP[(c4 * 4 + 1) * 8 + t] = p.y;
        sP[(c4 * 4 + 2) * 8 + t] = p.z;
        sP[(c4 * 4 + 3) * 8 + t] = p.w;
    }
    __syncthreads();

    const float4* x4 = (const float4*)x;
    float4 acc[8];
    #pragma unroll
    for (int t = 0; t < 8; ++t) acc[t] = make_float4(0.f, 0.f, 0.f, 0.f);

    #pragma unroll 4
    for (int si = 0; si < 64; ++si) {
        const int s = w * 64 + si;
        const float4 xv  = x4[(b * SEQ + s) * 64 + lane];
        const float4 p03 = *(const float4*)&sP[s * 8];
        const float4 p47 = *(const float4*)&sP[s * 8 + 4];
        acc[0].x = fmaf(p03.x, xv.x, acc[0].x); acc[0].y = fmaf(p03.x, xv.y, acc[0].y);
        acc[0].z = fmaf(p03.x, xv.z, acc[0].z); acc[0].w = fmaf(p03.x, xv.w, acc[0].w);
        acc[1].x = fmaf(p03.y, xv.x, acc[1].x); acc[1].y = fmaf(p03.y, xv.y, acc[1].y);
        acc[1].z = fmaf(p03.y, xv.z, acc[1].z); acc[1].w = fmaf(p03.y, xv.w, acc[1].w);
        acc[2].x = fmaf(p03.z, xv.x, acc[2].x); acc[2].y = fmaf(p03.z, xv.y, acc[2].y);
        acc[2].z = fmaf(p03.z, xv.z, acc[2].z); acc[2].w = fmaf(p03.z, xv.w, acc[2].w);
        acc[3].x = fmaf(p03.w, xv.x, acc[3].x); acc[3].y = fmaf(p03.w, xv.y, acc[3].y);
        acc[3].z = fmaf(p03.w, xv.z, acc[3].z); acc[3].w = fmaf(p03.w, xv.w, acc[3].w);
        acc[4].x = fmaf(p47.x, xv.x, acc[4].x); acc[4].y = fmaf(p47.x, xv.y, acc[4].y);
        acc[4].z = fmaf(p47.x, xv.z, acc[4].z); acc[4].w = fmaf(p47.x, xv.w, acc[4].w);
        acc[5].x = fmaf(p47.y, xv.x, acc[5].x); acc[5].y = fmaf(p47.y, xv.y, acc[5].y);
        acc[5].z = fmaf(p47.y, xv.z, acc[5].z); acc[5].w = fmaf(p47.y, xv.w, acc[5].w);
        acc[6].x = fmaf(p47.z, xv.x, acc[6].x); acc[6].y = fmaf(p47.z, xv.y, acc[6].y);
        acc[6].z = fmaf(p47.z, xv.z, acc[6].z); acc[6].w = fmaf(p47.z, xv.w, acc[6].w);
        acc[7].x = fmaf(p47.w, xv.x, acc[7].x); acc[7].y = fmaf(p47.w, xv.y, acc[7].y);
        acc[7].z = fmaf(p47.w, xv.z, acc[7].z); acc[7].w = fmaf(p47.w, xv.w, acc[7].w);
    }
    __syncthreads();
    float4* sRed4 = (float4*)sRed;     // [8 w][8 t][64 lanes]
    #pragma unroll
    for (int t = 0; t < 8; ++t)
        sRed4[w * 512 + t * 64 + lane] = acc[t];
    __syncthreads();
    #pragma unroll
    for (int j = 0; j < 4; ++j) {
        const int i = tid + j * 512;   // [0,2048): t = i>>8, d = i&255
        const int t = i >> 8, d = i & 255;
        const float r = sRed[0*2048 + t*256 + d] + sRed[1*2048 + t*256 + d]
                      + sRed[2*2048 + t*256 + d] + sRed[3*2048 + t*256 + d]
                      + sRed[4*2048 + t*256 + d] + sRed[5*2048 + t*256 + d]
                      + sRed[6*2048 + t*256 + d] + sRed[7*2048 + t*256 + d];
        out[(b * SEQ + t0 + t) * DDIM + d] = r;
    }
}

extern "C" void kernel_launch(void* const* d_in, const int* in_sizes, int n_in,
                              void* d_out, int out_size, void* d_ws, size_t ws_size,
                              hipStream_t stream) {
    const float* x   = (const float*)d_in[0];   // (4,512,256)
    const float* y   = (const float*)d_in[1];   // (4,512,256)
    const float* W1  = (const float*)d_in[2];   // (128,256)
    const float* W2  = (const float*)d_in[3];   // (128,256)
    const float* vc  = (const float*)d_in[4];   // (1,128)
    float* outp = (float*)d_out;                // (4,512,256)

    float* ws = (float*)d_ws;
    float* e1 = ws;                             // 1 MB (swizzled)
    float* e2 = ws + NB * SEQ * HDIM;           // 1 MB
    float* P  = ws + 2 * NB * SEQ * HDIM;       // 4 MB

    hipLaunchKernelGGL(proj_kernel,  dim3(512), dim3(256),  0, stream,
                       x, y, W1, W2, e1, e2);
    hipLaunchKernelGGL(score_kernel, dim3(512), dim3(1024), 0, stream,
                       e1, e2, vc, P);
    hipLaunchKernelGGL(pax_kernel,   dim3(256), dim3(512),  0, stream,
                       P, x, outp);
}

// Round 2
// 108.480 us; speedup vs baseline: 1.6924x; 1.6924x over previous
//
#include <hip/hip_runtime.h>

// B=4, Sx=Sy=512, H=128, D=2H=256, fp32.
// e1 = exp2(2log2e * x@W1^T)  (stored PRE-SWIZZLED: [b][c][hq][s^hq] float4)
// e2 = exp2(2log2e * y@W2^T)  (linear)
// tanh(s1+s2) = 1 - 2/(e1*e2+1); score = sum_h vc[h]*tanh(.)
// constant sum_h vc[h] dropped (softmax shift-invariant); -2 folded into the
// chunk reduce. P = softmax_s(score); out = P @ x.
// Quad-rcp: v1/f1+..+v4/f4 = (n12*f34+n34*f12)/(f12*f34), one rcp per 4 h.
//
// R8: harness 256 MiB d_ws fill = ~40 us of every timed iteration (fixed tax).
// R9: pax rewrite (1 b128 global + 2 b128 LDS per 32 FMAs).
// R10: score t=4/block (512 blk x 1024 thr).
// R11: FAILED (183us): LDS atomicAdd cross-wave reduce = 16-way collision on
//      256 addrs -> score 96us, VALUBusy 14.5%. Lesson: no LDS float atomics
//      under contention.
// R12: (a) score: G=16 wave layout means ZERO intra-block e1 reuse -> drop
//      sE1 staging + DMA + atomics entirely. Waves load e1 direct from
//      global (L2-resident, swizzle keeps it coalesced); deterministic
//      R10-style deferred reduce via double-buffered sPartC (32KB), one
//      barrier per chunk. LDS 72->40 KB.
//      (b) proj fused A1+A2 (R11) kept; pax 512-thr (R11) kept.

#define NB 4
#define SEQ 512
#define HDIM 128
#define DDIM 256

static constexpr float TWO_LOG2E = 2.8853900817779268f; // 2*log2(e)
static constexpr float LOG2E     = 1.4426950408889634f;

// ---------------- Kernel A: fused projection + exp2 -----------------------
// 512 blocks x 256 thr. Block = 8 rows of x (gr0<2048) or y, full K=256.
// Epilogue applies exp2 and writes e1 swizzled / e2 linear directly.
__global__ __launch_bounds__(256) void proj_kernel(
    const float* __restrict__ x, const float* __restrict__ y,
    const float* __restrict__ W1, const float* __restrict__ W2,
    float* __restrict__ e1sw, float* __restrict__ e2)
{
    __shared__ float As[2048];      // [8 r][256 k]
    __shared__ float sPr[8192];     // [8 ks][8 r][128 h]
    const int tid = threadIdx.x;
    const int gr0 = blockIdx.x * 8;       // global virtual row base [0,4096)

    const float* in; const float* W; int srow;
    if (gr0 < 2048) { in = x; W = W1; srow = gr0; }
    else            { in = y; W = W2; srow = gr0 - 2048; }

    #pragma unroll
    for (int j = 0; j < 2; ++j) {
        const int idx = tid + j * 256;        // float4 slot [0,512)
        const int r = idx >> 6, kk = idx & 63;
        *(float4*)&As[idx * 4] =
            *(const float4*)&in[(srow + r) * 256 + kk * 4];
    }
    __syncthreads();

    const int hq = tid & 31;   // h-quad
    const int ks = tid >> 5;   // k-slice of 32

    float4 acc4[8];
    #pragma unroll
    for (int r = 0; r < 8; ++r) acc4[r] = make_float4(0.f, 0.f, 0.f, 0.f);

    #pragma unroll
    for (int u = 0; u < 8; ++u) {
        const int kof = ks * 32 + u * 4;
        const float4 w0 = *(const float4*)&W[(4*hq + 0) * 256 + kof];
        const float4 w1 = *(const float4*)&W[(4*hq + 1) * 256 + kof];
        const float4 w2 = *(const float4*)&W[(4*hq + 2) * 256 + kof];
        const float4 w3 = *(const float4*)&W[(4*hq + 3) * 256 + kof];
        #pragma unroll
        for (int r = 0; r < 8; ++r) {
            const float4 a = *(const float4*)&As[r * 256 + kof];
            acc4[r].x = fmaf(a.w,w0.w, fmaf(a.z,w0.z, fmaf(a.y,w0.y, fmaf(a.x,w0.x, acc4[r].x))));
            acc4[r].y = fmaf(a.w,w1.w, fmaf(a.z,w1.z, fmaf(a.y,w1.y, fmaf(a.x,w1.x, acc4[r].y))));
            acc4[r].z = fmaf(a.w,w2.w, fmaf(a.z,w2.z, fmaf(a.y,w2.y, fmaf(a.x,w2.x, acc4[r].z))));
            acc4[r].w = fmaf(a.w,w3.w, fmaf(a.z,w3.z, fmaf(a.y,w3.y, fmaf(a.x,w3.x, acc4[r].w))));
        }
    }
    #pragma unroll
    for (int r = 0; r < 8; ++r)
        *(float4*)&sPr[ks * 1024 + r * 128 + hq * 4] = acc4[r];
    __syncthreads();
    {
        const int r = tid >> 5, h4 = tid & 31;
        float4 s = make_float4(0.f, 0.f, 0.f, 0.f);
        #pragma unroll
        for (int k2 = 0; k2 < 8; ++k2) {
            const float4 p = *(const float4*)&sPr[k2 * 1024 + r * 128 + h4 * 4];
            s.x += p.x; s.y += p.y; s.z += p.z; s.w += p.w;
        }
        float4 o;
        o.x = __builtin_amdgcn_exp2f(s.x * TWO_LOG2E);
        o.y = __builtin_amdgcn_exp2f(s.y * TWO_LOG2E);
        o.z = __builtin_amdgcn_exp2f(s.z * TWO_LOG2E);
        o.w = __builtin_amdgcn_exp2f(s.w * TWO_LOG2E);
        const int gr = gr0 + r;
        if (gr < 2048) {
            const int b = gr >> 9, ss = gr & 511;
            const int c = ss >> 6, sl = ss & 63;
            ((float4*)e1sw)[((b * 8 + c) * 32 + h4) * 64 + (sl ^ h4)] = o;
        } else {
            ((float4*)e2)[(gr - 2048) * 32 + h4] = o;
        }
    }
}

// ---------------- Kernel B: scores + softmax -> P --------------------------
// 512 blocks x 1024 thr (16 waves). Block = (b, 4 t). Wave w = h-group of
// 8 h (quads 2w, 2w+1); each wave computes ALL 4 t per e1 value. e1 read
// DIRECTLY from global (L2-resident; swizzled layout keeps lane reads inside
// one 1KB segment -> fully coalesced). e2/vc in SGPRs (uniform addrs via
// readfirstlane). Cross-wave reduce: double-buffered sPartC, one barrier per
// chunk; waves 0-3 reduce chunk c while 4-15 start c+1. LDS 40 KB ->
// 2 blocks/CU = 32 waves/CU.
__global__ __launch_bounds__(1024) void score_kernel(
    const float* __restrict__ e1sw, const float* __restrict__ e2g,
    const float* __restrict__ vc,  float* __restrict__ P)
{
    __shared__ float sPartC[2][16 * 256];  // 32 KB: [buf][w][t][64 s]
    __shared__ float sScore[4 * 512];      // 8 KB:  [t][512 s]

    const int tid  = threadIdx.x;
    const int b    = blockIdx.x >> 7;
    const int t0   = (blockIdx.x & 127) * 4;
    const int w    = tid >> 6;
    const int lane = tid & 63;
    const int wu   = __builtin_amdgcn_readfirstlane(w);
    const int hg   = wu;               // h-group: quads 2hg, 2hg+1

    // scalar operands: 2 vc quads + 4t x 2 e2 quads -> SGPRs
    float4 vcs[2];
    float4 e2s[4][2];
    #pragma unroll
    for (int j = 0; j < 2; ++j)
        vcs[j] = *(const float4*)&vc[(hg * 2 + j) * 4];
    #pragma unroll
    for (int t = 0; t < 4; ++t)
        #pragma unroll
        for (int j = 0; j < 2; ++j)
            e2s[t][j] = *(const float4*)&e2g[(b * SEQ + t0 + t) * HDIM + (hg * 2 + j) * 4];

    const float4* e1c = (const float4*)e1sw + b * 16384;  // 8 chunks x 2048

    for (int c = 0; c < 8; ++c) {
        const float4* chunk = e1c + c * 2048;
        float acc0 = 0.f, acc1 = 0.f, acc2 = 0.f, acc3 = 0.f;
        #pragma unroll
        for (int j = 0; j < 2; ++j) {
            const int hq = hg * 2 + j;
            const float4 e1 = chunk[hq * 64 + (lane ^ hq)];
            const float4 vv = vcs[j];
            #pragma unroll
            for (int t = 0; t < 4; ++t) {
                const float4 e2 = e2s[t][j];
                const float f1 = fmaf(e1.x, e2.x, 1.f);
                const float f2 = fmaf(e1.y, e2.y, 1.f);
                const float f3 = fmaf(e1.z, e2.z, 1.f);
                const float f4 = fmaf(e1.w, e2.w, 1.f);
                const float f12 = f1 * f2, f34 = f3 * f4;
                const float n12 = fmaf(vv.x, f2, vv.y * f1);
                const float n34 = fmaf(vv.z, f4, vv.w * f3);
                const float num = fmaf(n12, f34, n34 * f12);
                const float r = fmaf(num, __builtin_amdgcn_rcpf(f12 * f34),
                                     (t == 0) ? acc0 : (t == 1) ? acc1 : (t == 2) ? acc2 : acc3);
                if      (t == 0) acc0 = r;
                else if (t == 1) acc1 = r;
                else if (t == 2) acc2 = r;
                else             acc3 = r;
            }
        }
        float* pb = sPartC[c & 1] + wu * 256 + lane;
        pb[0 * 64] = acc0;
        pb[1 * 64] = acc1;
        pb[2 * 64] = acc2;
        pb[3 * 64] = acc3;
        __syncthreads();
        if (tid < 256) {
            const int t = tid >> 6, s = tid & 63;
            const float* pc = sPartC[c & 1] + t * 64 + s;
            float r = 0.f;
            #pragma unroll
            for (int ww = 0; ww < 16; ++ww) r += pc[ww * 256];
            sScore[t * 512 + c * 64 + s] = -2.f * r;
        }
    }
    __syncthreads();

    // softmax: waves 0..3 -> t0+w; write normalized P
    if (w < 4) {
        float v[8];
        float m = -1e30f;
        #pragma unroll
        for (int j = 0; j < 8; ++j) {
            v[j] = sScore[w * 512 + lane + j * 64];
            m = fmaxf(m, v[j]);
        }
        #pragma unroll
        for (int off = 32; off; off >>= 1) m = fmaxf(m, __shfl_xor(m, off));
        float sum = 0.f;
        #pragma unroll
        for (int j = 0; j < 8; ++j) {
            v[j] = __builtin_amdgcn_exp2f((v[j] - m) * LOG2E);
            sum += v[j];
        }
        #pragma unroll
        for (int off = 32; off; off >>= 1) sum += __shfl_xor(sum, off);
        const float inv = __builtin_amdgcn_rcpf(sum);
        float* Prow = &P[(b * SEQ + t0 + w) * SEQ];
        #pragma unroll
        for (int j = 0; j < 8; ++j)
            Prow[lane + j * 64] = v[j] * inv;
    }
}

// ---------------- Kernel C: out = P @ x ------------------------------------
// 256 blocks x 512 thr (8 waves, 2/SIMD). Wave w covers s in [64w, 64w+64);
// 8-way sRed reduce. LDS 80 KB.
__global__ __launch_bounds__(512) void pax_kernel(
    const float* __restrict__ P, const float* __restrict__ x,
    float* __restrict__ out)
{
    __shared__ float sP[SEQ * 8];        // 16 KB: [s][t]
    __shared__ float sRed[8 * 8 * DDIM]; // 64 KB: [w][t][d]
    const int tid = threadIdx.x;
    const int b   = blockIdx.x >> 6;
    const int t0  = (blockIdx.x & 63) * 8;
    const int w    = tid >> 6;
    const int lane = tid & 63;

    #pragma unroll
    for (int j = 0; j < 2; ++j) {
        const int i = tid + j * 512;          // [0,1024): t = i>>7, c4 = i&127
        const int t = i >> 7, c4 = i & 127;
        const float4 p = *(const float4*)&P[(b * SEQ + t0 + t) * SEQ + c4 * 4];
        sP[(c4 * 4 + 0) * 8 + t] = p.x;
        sP[(c4 * 4 + 1) * 8 + t] = p.y;
        sP[(c4 * 4 + 2) * 8 + t] = p.z;
        sP[(c4 * 4 + 3) * 8 + t] = p.w;
    }
    __syncthreads();

    const float4* x4 = (const float4*)x;
    float4 acc[8];
    #pragma unroll
    for (int t = 0; t < 8; ++t) acc[t] = make_float4(0.f, 0.f, 0.f, 0.f);

    #pragma unroll 4
    for (int si = 0; si < 64; ++si) {
        const int s = w * 64 + si;
        const float4 xv  = x4[(b * SEQ + s) * 64 + lane];
        const float4 p03 = *(const float4*)&sP[s * 8];
        const float4 p47 = *(const float4*)&sP[s * 8 + 4];
        acc[0].x = fmaf(p03.x, xv.x, acc[0].x); acc[0].y = fmaf(p03.x, xv.y, acc[0].y);
        acc[0].z = fmaf(p03.x, xv.z, acc[0].z); acc[0].w = fmaf(p03.x, xv.w, acc[0].w);
        acc[1].x = fmaf(p03.y, xv.x, acc[1].x); acc[1].y = fmaf(p03.y, xv.y, acc[1].y);
        acc[1].z = fmaf(p03.y, xv.z, acc[1].z); acc[1].w = fmaf(p03.y, xv.w, acc[1].w);
        acc[2].x = fmaf(p03.z, xv.x, acc[2].x); acc[2].y = fmaf(p03.z, xv.y, acc[2].y);
        acc[2].z = fmaf(p03.z, xv.z, acc[2].z); acc[2].w = fmaf(p03.z, xv.w, acc[2].w);
        acc[3].x = fmaf(p03.w, xv.x, acc[3].x); acc[3].y = fmaf(p03.w, xv.y, acc[3].y);
        acc[3].z = fmaf(p03.w, xv.z, acc[3].z); acc[3].w = fmaf(p03.w, xv.w, acc[3].w);
        acc[4].x = fmaf(p47.x, xv.x, acc[4].x); acc[4].y = fmaf(p47.x, xv.y, acc[4].y);
        acc[4].z = fmaf(p47.x, xv.z, acc[4].z); acc[4].w = fmaf(p47.x, xv.w, acc[4].w);
        acc[5].x = fmaf(p47.y, xv.x, acc[5].x); acc[5].y = fmaf(p47.y, xv.y, acc[5].y);
        acc[5].z = fmaf(p47.y, xv.z, acc[5].z); acc[5].w = fmaf(p47.y, xv.w, acc[5].w);
        acc[6].x = fmaf(p47.z, xv.x, acc[6].x); acc[6].y = fmaf(p47.z, xv.y, acc[6].y);
        acc[6].z = fmaf(p47.z, xv.z, acc[6].z); acc[6].w = fmaf(p47.z, xv.w, acc[6].w);
        acc[7].x = fmaf(p47.w, xv.x, acc[7].x); acc[7].y = fmaf(p47.w, xv.y, acc[7].y);
        acc[7].z = fmaf(p47.w, xv.z, acc[7].z); acc[7].w = fmaf(p47.w, xv.w, acc[7].w);
    }
    __syncthreads();
    float4* sRed4 = (float4*)sRed;     // [8 w][8 t][64 lanes]
    #pragma unroll
    for (int t = 0; t < 8; ++t)
        sRed4[w * 512 + t * 64 + lane] = acc[t];
    __syncthreads();
    #pragma unroll
    for (int j = 0; j < 4; ++j) {
        const int i = tid + j * 512;   // [0,2048): t = i>>8, d = i&255
        const int t = i >> 8, d = i & 255;
        const float r = sRed[0*2048 + t*256 + d] + sRed[1*2048 + t*256 + d]
                      + sRed[2*2048 + t*256 + d] + sRed[3*2048 + t*256 + d]
                      + sRed[4*2048 + t*256 + d] + sRed[5*2048 + t*256 + d]
                      + sRed[6*2048 + t*256 + d] + sRed[7*2048 + t*256 + d];
        out[(b * SEQ + t0 + t) * DDIM + d] = r;
    }
}

extern "C" void kernel_launch(void* const* d_in, const int* in_sizes, int n_in,
                              void* d_out, int out_size, void* d_ws, size_t ws_size,
                              hipStream_t stream) {
    const float* x   = (const float*)d_in[0];   // (4,512,256)
    const float* y   = (const float*)d_in[1];   // (4,512,256)
    const float* W1  = (const float*)d_in[2];   // (128,256)
    const float* W2  = (const float*)d_in[3];   // (128,256)
    const float* vc  = (const float*)d_in[4];   // (1,128)
    float* outp = (float*)d_out;                // (4,512,256)

    float* ws = (float*)d_ws;
    float* e1 = ws;                             // 1 MB (swizzled)
    float* e2 = ws + NB * SEQ * HDIM;           // 1 MB
    float* P  = ws + 2 * NB * SEQ * HDIM;       // 4 MB

    hipLaunchKernelGGL(proj_kernel,  dim3(512), dim3(256),  0, stream,
                       x, y, W1, W2, e1, e2);
    hipLaunchKernelGGL(score_kernel, dim3(512), dim3(1024), 0, stream,
                       e1, e2, vc, P);
    hipLaunchKernelGGL(pax_kernel,   dim3(256), dim3(512),  0, stream,
                       P, x, outp);
}

// Round 3
// 99.342 us; speedup vs baseline: 1.8481x; 1.0920x over previous
//
#include <hip/hip_runtime.h>

// B=4, Sx=Sy=512, H=128, D=2H=256, fp32.
// e1 = exp2(2log2e * x@W1^T)  (stored PRE-SWIZZLED: [b][c][hq][s^hq] float4)
// e2 = exp2(2log2e * y@W2^T)  (linear)
// tanh(s1+s2) = 1 - 2/(e1*e2+1); score = sum_h vc[h]*tanh(.)
// constant sum_h vc[h] dropped (softmax shift-invariant); -2 folded into the
// chunk reduce. P = softmax_s(score); out = P @ x.
// Quad-rcp: v1/f1+..+v4/f4 = (n12*f34+n34*f12)/(f12*f34), one rcp per 4 h.
//
// R8: harness 256 MiB d_ws fill = ~40 us of every timed iteration (fixed tax).
// R9: pax rewrite (1 b128 global + 2 b128 LDS per 32 FMAs).
// R10: score t=4/block (512 blk x 1024 thr).
// R11: FAILED (183us): LDS atomicAdd cross-wave reduce = 16-way collision ->
//      score 96us, VALUBusy 14.5%. Lesson: no LDS float atomics under
//      contention.
// R12: score reads e1 direct from global (zero intra-block reuse in G=16
//      layout -> staging was pure overhead); deterministic sPartC reduce.
//      108.5us.
// R13: proj W-loads were fully UNCOALESCED (lanes 4KB apart; ~64 lines per
//      wave-load, ~13us of VMEM address processing). Fix: tiny wtrans kernel
//      pre-transposes W into Wt[k][h-quad] float4 layout; proj W-loads become
//      lane-consecutive (512B/half-wave). Same FLOPs/regs/LDS; FMA
//      re-associated. score/pax byte-identical to R12 for attribution.

#define NB 4
#define SEQ 512
#define HDIM 128
#define DDIM 256

static constexpr float TWO_LOG2E = 2.8853900817779268f; // 2*log2(e)
static constexpr float LOG2E     = 1.4426950408889634f;

// ---------------- Kernel W: transpose W1/W2 -> Wt[k][h] --------------------
// 16 blocks (2 W x 8 k-slices of 32 k) x 256 thr. Wt4[k*32 + hq] =
// {W[4hq+0][k], W[4hq+1][k], W[4hq+2][k], W[4hq+3][k]}.
__global__ __launch_bounds__(256) void wtrans_kernel(
    const float* __restrict__ W1, const float* __restrict__ W2,
    float* __restrict__ Wt1, float* __restrict__ Wt2)
{
    __shared__ float sT[32 * 132];   // [k_local][h], pad 132
    const int blk = blockIdx.x;
    const int which = blk >> 3;
    const int s = blk & 7;           // k-slice: k = s*32 + [0,32)
    const float* W  = which ? W2 : W1;
    float*       Wt = which ? Wt2 : Wt1;
    const int tid = threadIdx.x;

    #pragma unroll
    for (int i = 0; i < 4; ++i) {
        const int idx = i * 256 + tid;       // [0,1024)
        const int h = idx >> 3, k4 = idx & 7;
        const float4 v = ((const float4*)W)[h * 64 + s * 8 + k4];
        sT[(k4 * 4 + 0) * 132 + h] = v.x;
        sT[(k4 * 4 + 1) * 132 + h] = v.y;
        sT[(k4 * 4 + 2) * 132 + h] = v.z;
        sT[(k4 * 4 + 3) * 132 + h] = v.w;
    }
    __syncthreads();
    #pragma unroll
    for (int i = 0; i < 4; ++i) {
        const int idx = i * 256 + tid;       // [0,1024)
        const int kl = idx >> 5, hq = idx & 31;
        float4 o;
        o.x = sT[kl * 132 + 4 * hq + 0];
        o.y = sT[kl * 132 + 4 * hq + 1];
        o.z = sT[kl * 132 + 4 * hq + 2];
        o.w = sT[kl * 132 + 4 * hq + 3];
        ((float4*)Wt)[(s * 32 + kl) * 32 + hq] = o;
    }
}

// ---------------- Kernel A: fused projection + exp2 -----------------------
// 512 blocks x 256 thr. Block = 8 rows of x (gr0<2048) or y, full K=256.
// W read from TRANSPOSED Wt (coalesced: lanes hq consecutive float4).
// Epilogue applies exp2 and writes e1 swizzled / e2 linear directly.
__global__ __launch_bounds__(256) void proj_kernel(
    const float* __restrict__ x, const float* __restrict__ y,
    const float* __restrict__ Wt1, const float* __restrict__ Wt2,
    float* __restrict__ e1sw, float* __restrict__ e2)
{
    __shared__ float As[2048];      // [8 r][256 k]
    __shared__ float sPr[8192];     // [8 ks][8 r][128 h]
    const int tid = threadIdx.x;
    const int gr0 = blockIdx.x * 8;       // global virtual row base [0,4096)

    const float* in; const float* Wt; int srow;
    if (gr0 < 2048) { in = x; Wt = Wt1; srow = gr0; }
    else            { in = y; Wt = Wt2; srow = gr0 - 2048; }

    #pragma unroll
    for (int j = 0; j < 2; ++j) {
        const int idx = tid + j * 256;        // float4 slot [0,512)
        const int r = idx >> 6, kk = idx & 63;
        *(float4*)&As[idx * 4] =
            *(const float4*)&in[(srow + r) * 256 + kk * 4];
    }
    __syncthreads();

    const int hq = tid & 31;   // h-quad
    const int ks = tid >> 5;   // k-slice of 32
    const float4* Wt4 = (const float4*)Wt;

    float4 acc4[8];
    #pragma unroll
    for (int r = 0; r < 8; ++r) acc4[r] = make_float4(0.f, 0.f, 0.f, 0.f);

    #pragma unroll
    for (int u = 0; u < 8; ++u) {
        const int kof = ks * 32 + u * 4;
        // w_j = h-quad {4hq..4hq+3} at k = kof+j  (lane-consecutive float4s)
        const float4 w0 = Wt4[(kof + 0) * 32 + hq];
        const float4 w1 = Wt4[(kof + 1) * 32 + hq];
        const float4 w2 = Wt4[(kof + 2) * 32 + hq];
        const float4 w3 = Wt4[(kof + 3) * 32 + hq];
        #pragma unroll
        for (int r = 0; r < 8; ++r) {
            const float4 a = *(const float4*)&As[r * 256 + kof];
            acc4[r].x = fmaf(a.w,w3.x, fmaf(a.z,w2.x, fmaf(a.y,w1.x, fmaf(a.x,w0.x, acc4[r].x))));
            acc4[r].y = fmaf(a.w,w3.y, fmaf(a.z,w2.y, fmaf(a.y,w1.y, fmaf(a.x,w0.y, acc4[r].y))));
            acc4[r].z = fmaf(a.w,w3.z, fmaf(a.z,w2.z, fmaf(a.y,w1.z, fmaf(a.x,w0.z, acc4[r].z))));
            acc4[r].w = fmaf(a.w,w3.w, fmaf(a.z,w2.w, fmaf(a.y,w1.w, fmaf(a.x,w0.w, acc4[r].w))));
        }
    }
    #pragma unroll
    for (int r = 0; r < 8; ++r)
        *(float4*)&sPr[ks * 1024 + r * 128 + hq * 4] = acc4[r];
    __syncthreads();
    {
        const int r = tid >> 5, h4 = tid & 31;
        float4 s = make_float4(0.f, 0.f, 0.f, 0.f);
        #pragma unroll
        for (int k2 = 0; k2 < 8; ++k2) {
            const float4 p = *(const float4*)&sPr[k2 * 1024 + r * 128 + h4 * 4];
            s.x += p.x; s.y += p.y; s.z += p.z; s.w += p.w;
        }
        float4 o;
        o.x = __builtin_amdgcn_exp2f(s.x * TWO_LOG2E);
        o.y = __builtin_amdgcn_exp2f(s.y * TWO_LOG2E);
        o.z = __builtin_amdgcn_exp2f(s.z * TWO_LOG2E);
        o.w = __builtin_amdgcn_exp2f(s.w * TWO_LOG2E);
        const int gr = gr0 + r;
        if (gr < 2048) {
            const int b = gr >> 9, ss = gr & 511;
            const int c = ss >> 6, sl = ss & 63;
            ((float4*)e1sw)[((b * 8 + c) * 32 + h4) * 64 + (sl ^ h4)] = o;
        } else {
            ((float4*)e2)[(gr - 2048) * 32 + h4] = o;
        }
    }
}

// ---------------- Kernel B: scores + softmax -> P --------------------------
// 512 blocks x 1024 thr (16 waves). Block = (b, 4 t). Wave w = h-group of
// 8 h (quads 2w, 2w+1); each wave computes ALL 4 t per e1 value. e1 read
// DIRECTLY from global (L2-resident; swizzled layout keeps lane reads inside
// one 1KB segment -> fully coalesced). e2/vc in SGPRs (uniform addrs via
// readfirstlane). Cross-wave reduce: double-buffered sPartC, one barrier per
// chunk; waves 0-3 reduce chunk c while 4-15 start c+1. LDS 40 KB ->
// 2 blocks/CU = 32 waves/CU.
__global__ __launch_bounds__(1024) void score_kernel(
    const float* __restrict__ e1sw, const float* __restrict__ e2g,
    const float* __restrict__ vc,  float* __restrict__ P)
{
    __shared__ float sPartC[2][16 * 256];  // 32 KB: [buf][w][t][64 s]
    __shared__ float sScore[4 * 512];      // 8 KB:  [t][512 s]

    const int tid  = threadIdx.x;
    const int b    = blockIdx.x >> 7;
    const int t0   = (blockIdx.x & 127) * 4;
    const int w    = tid >> 6;
    const int lane = tid & 63;
    const int wu   = __builtin_amdgcn_readfirstlane(w);
    const int hg   = wu;               // h-group: quads 2hg, 2hg+1

    // scalar operands: 2 vc quads + 4t x 2 e2 quads -> SGPRs
    float4 vcs[2];
    float4 e2s[4][2];
    #pragma unroll
    for (int j = 0; j < 2; ++j)
        vcs[j] = *(const float4*)&vc[(hg * 2 + j) * 4];
    #pragma unroll
    for (int t = 0; t < 4; ++t)
        #pragma unroll
        for (int j = 0; j < 2; ++j)
            e2s[t][j] = *(const float4*)&e2g[(b * SEQ + t0 + t) * HDIM + (hg * 2 + j) * 4];

    const float4* e1c = (const float4*)e1sw + b * 16384;  // 8 chunks x 2048

    for (int c = 0; c < 8; ++c) {
        const float4* chunk = e1c + c * 2048;
        float acc0 = 0.f, acc1 = 0.f, acc2 = 0.f, acc3 = 0.f;
        #pragma unroll
        for (int j = 0; j < 2; ++j) {
            const int hq = hg * 2 + j;
            const float4 e1 = chunk[hq * 64 + (lane ^ hq)];
            const float4 vv = vcs[j];
            #pragma unroll
            for (int t = 0; t < 4; ++t) {
                const float4 e2 = e2s[t][j];
                const float f1 = fmaf(e1.x, e2.x, 1.f);
                const float f2 = fmaf(e1.y, e2.y, 1.f);
                const float f3 = fmaf(e1.z, e2.z, 1.f);
                const float f4 = fmaf(e1.w, e2.w, 1.f);
                const float f12 = f1 * f2, f34 = f3 * f4;
                const float n12 = fmaf(vv.x, f2, vv.y * f1);
                const float n34 = fmaf(vv.z, f4, vv.w * f3);
                const float num = fmaf(n12, f34, n34 * f12);
                const float r = fmaf(num, __builtin_amdgcn_rcpf(f12 * f34),
                                     (t == 0) ? acc0 : (t == 1) ? acc1 : (t == 2) ? acc2 : acc3);
                if      (t == 0) acc0 = r;
                else if (t == 1) acc1 = r;
                else if (t == 2) acc2 = r;
                else             acc3 = r;
            }
        }
        float* pb = sPartC[c & 1] + wu * 256 + lane;
        pb[0 * 64] = acc0;
        pb[1 * 64] = acc1;
        pb[2 * 64] = acc2;
        pb[3 * 64] = acc3;
        __syncthreads();
        if (tid < 256) {
            const int t = tid >> 6, s = tid & 63;
            const float* pc = sPartC[c & 1] + t * 64 + s;
            float r = 0.f;
            #pragma unroll
            for (int ww = 0; ww < 16; ++ww) r += pc[ww * 256];
            sScore[t * 512 + c * 64 + s] = -2.f * r;
        }
    }
    __syncthreads();

    // softmax: waves 0..3 -> t0+w; write normalized P
    if (w < 4) {
        float v[8];
        float m = -1e30f;
        #pragma unroll
        for (int j = 0; j < 8; ++j) {
            v[j] = sScore[w * 512 + lane + j * 64];
            m = fmaxf(m, v[j]);
        }
        #pragma unroll
        for (int off = 32; off; off >>= 1) m = fmaxf(m, __shfl_xor(m, off));
        float sum = 0.f;
        #pragma unroll
        for (int j = 0; j < 8; ++j) {
            v[j] = __builtin_amdgcn_exp2f((v[j] - m) * LOG2E);
            sum += v[j];
        }
        #pragma unroll
        for (int off = 32; off; off >>= 1) sum += __shfl_xor(sum, off);
        const float inv = __builtin_amdgcn_rcpf(sum);
        float* Prow = &P[(b * SEQ + t0 + w) * SEQ];
        #pragma unroll
        for (int j = 0; j < 8; ++j)
            Prow[lane + j * 64] = v[j] * inv;
    }
}

// ---------------- Kernel C: out = P @ x ------------------------------------
// 256 blocks x 512 thr (8 waves, 2/SIMD). Wave w covers s in [64w, 64w+64);
// 8-way sRed reduce. LDS 80 KB.
__global__ __launch_bounds__(512) void pax_kernel(
    const float* __restrict__ P, const float* __restrict__ x,
    float* __restrict__ out)
{
    __shared__ float sP[SEQ * 8];        // 16 KB: [s][t]
    __shared__ float sRed[8 * 8 * DDIM]; // 64 KB: [w][t][d]
    const int tid = threadIdx.x;
    const int b   = blockIdx.x >> 6;
    const int t0  = (blockIdx.x & 63) * 8;
    const int w    = tid >> 6;
    const int lane = tid & 63;

    #pragma unroll
    for (int j = 0; j < 2; ++j) {
        const int i = tid + j * 512;          // [0,1024): t = i>>7, c4 = i&127
        const int t = i >> 7, c4 = i & 127;
        const float4 p = *(const float4*)&P[(b * SEQ + t0 + t) * SEQ + c4 * 4];
        sP[(c4 * 4 + 0) * 8 + t] = p.x;
        sP[(c4 * 4 + 1) * 8 + t] = p.y;
        sP[(c4 * 4 + 2) * 8 + t] = p.z;
        sP[(c4 * 4 + 3) * 8 + t] = p.w;
    }
    __syncthreads();

    const float4* x4 = (const float4*)x;
    float4 acc[8];
    #pragma unroll
    for (int t = 0; t < 8; ++t) acc[t] = make_float4(0.f, 0.f, 0.f, 0.f);

    #pragma unroll 4
    for (int si = 0; si < 64; ++si) {
        const int s = w * 64 + si;
        const float4 xv  = x4[(b * SEQ + s) * 64 + lane];
        const float4 p03 = *(const float4*)&sP[s * 8];
        const float4 p47 = *(const float4*)&sP[s * 8 + 4];
        acc[0].x = fmaf(p03.x, xv.x, acc[0].x); acc[0].y = fmaf(p03.x, xv.y, acc[0].y);
        acc[0].z = fmaf(p03.x, xv.z, acc[0].z); acc[0].w = fmaf(p03.x, xv.w, acc[0].w);
        acc[1].x = fmaf(p03.y, xv.x, acc[1].x); acc[1].y = fmaf(p03.y, xv.y, acc[1].y);
        acc[1].z = fmaf(p03.y, xv.z, acc[1].z); acc[1].w = fmaf(p03.y, xv.w, acc[1].w);
        acc[2].x = fmaf(p03.z, xv.x, acc[2].x); acc[2].y = fmaf(p03.z, xv.y, acc[2].y);
        acc[2].z = fmaf(p03.z, xv.z, acc[2].z); acc[2].w = fmaf(p03.z, xv.w, acc[2].w);
        acc[3].x = fmaf(p03.w, xv.x, acc[3].x); acc[3].y = fmaf(p03.w, xv.y, acc[3].y);
        acc[3].z = fmaf(p03.w, xv.z, acc[3].z); acc[3].w = fmaf(p03.w, xv.w, acc[3].w);
        acc[4].x = fmaf(p47.x, xv.x, acc[4].x); acc[4].y = fmaf(p47.x, xv.y, acc[4].y);
        acc[4].z = fmaf(p47.x, xv.z, acc[4].z); acc[4].w = fmaf(p47.x, xv.w, acc[4].w);
        acc[5].x = fmaf(p47.y, xv.x, acc[5].x); acc[5].y = fmaf(p47.y, xv.y, acc[5].y);
        acc[5].z = fmaf(p47.y, xv.z, acc[5].z); acc[5].w = fmaf(p47.y, xv.w, acc[5].w);
        acc[6].x = fmaf(p47.z, xv.x, acc[6].x); acc[6].y = fmaf(p47.z, xv.y, acc[6].y);
        acc[6].z = fmaf(p47.z, xv.z, acc[6].z); acc[6].w = fmaf(p47.z, xv.w, acc[6].w);
        acc[7].x = fmaf(p47.w, xv.x, acc[7].x); acc[7].y = fmaf(p47.w, xv.y, acc[7].y);
        acc[7].z = fmaf(p47.w, xv.z, acc[7].z); acc[7].w = fmaf(p47.w, xv.w, acc[7].w);
    }
    __syncthreads();
    float4* sRed4 = (float4*)sRed;     // [8 w][8 t][64 lanes]
    #pragma unroll
    for (int t = 0; t < 8; ++t)
        sRed4[w * 512 + t * 64 + lane] = acc[t];
    __syncthreads();
    #pragma unroll
    for (int j = 0; j < 4; ++j) {
        const int i = tid + j * 512;   // [0,2048): t = i>>8, d = i&255
        const int t = i >> 8, d = i & 255;
        const float r = sRed[0*2048 + t*256 + d] + sRed[1*2048 + t*256 + d]
                      + sRed[2*2048 + t*256 + d] + sRed[3*2048 + t*256 + d]
                      + sRed[4*2048 + t*256 + d] + sRed[5*2048 + t*256 + d]
                      + sRed[6*2048 + t*256 + d] + sRed[7*2048 + t*256 + d];
        out[(b * SEQ + t0 + t) * DDIM + d] = r;
    }
}

extern "C" void kernel_launch(void* const* d_in, const int* in_sizes, int n_in,
                              void* d_out, int out_size, void* d_ws, size_t ws_size,
                              hipStream_t stream) {
    const float* x   = (const float*)d_in[0];   // (4,512,256)
    const float* y   = (const float*)d_in[1];   // (4,512,256)
    const float* W1  = (const float*)d_in[2];   // (128,256)
    const float* W2  = (const float*)d_in[3];   // (128,256)
    const float* vc  = (const float*)d_in[4];   // (1,128)
    float* outp = (float*)d_out;                // (4,512,256)

    float* ws  = (float*)d_ws;
    float* e1  = ws;                            // 1 MB (swizzled)
    float* e2  = ws + NB * SEQ * HDIM;          // 1 MB
    float* P   = ws + 2 * NB * SEQ * HDIM;      // 4 MB
    float* Wt1 = P + NB * SEQ * SEQ;            // 128 KB
    float* Wt2 = Wt1 + HDIM * DDIM;             // 128 KB

    hipLaunchKernelGGL(wtrans_kernel, dim3(16),  dim3(256),  0, stream,
                       W1, W2, Wt1, Wt2);
    hipLaunchKernelGGL(proj_kernel,   dim3(512), dim3(256),  0, stream,
                       x, y, Wt1, Wt2, e1, e2);
    hipLaunchKernelGGL(score_kernel,  dim3(512), dim3(1024), 0, stream,
                       e1, e2, vc, P);
    hipLaunchKernelGGL(pax_kernel,    dim3(256), dim3(512),  0, stream,
                       P, x, outp);
}

// Round 4
// 97.980 us; speedup vs baseline: 1.8738x; 1.0139x over previous
//
#include <hip/hip_runtime.h>

// B=4, Sx=Sy=512, H=128, D=2H=256, fp32.
// e1 = exp2(2log2e * x@W1^T)  (stored PRE-SWIZZLED: [b][c][hq][s^hq] float4)
// e2 = exp2(2log2e * y@W2^T)  (linear)
// tanh(s1+s2) = 1 - 2/(e1*e2+1); score = sum_h vc[h]*tanh(.)
// constant sum_h vc[h] dropped (softmax shift-invariant); -2 folded into the
// chunk reduce. P = softmax_s(score); out = P @ x.
// Quad-rcp: v1/f1+..+v4/f4 = (n12*f34+n34*f12)/(f12*f34), one rcp per 4 h.
//
// R8: harness 256 MiB d_ws fill = ~40 us of every timed iteration (fixed tax).
// R11: FAILED: LDS float atomicAdd under 16-way collision -> score 96us.
// R12: score reads e1 direct from global (zero intra-block reuse in G=16
//      layout); deterministic sPartC reduce. 108.5us.
// R13: wtrans pre-transposes W (proj W-loads were lane-scattered, 64 lines
//      per wave-load). 99.3us. Attribution: fill 40, score ~21, rest ~38.
// R14: (a) score: VALU floor is 7.7us but runs ~21. Fix: e1 prefetch depth-1
//      (loads issued a chunk ahead, hides L2 latency) + barrier cadence
//      halved (2 chunks per barrier, 2x2-buffered sPartC 64KB, 512-thread
//      reduce). LDS 72KB -> still 2 blocks/CU.
//      (b) pax: was 1 block/CU x 8 waves (2/SIMD). Now 1024 thr: 16 waves,
//      each owns a unique 32-s strip and ALL 8 t (x read once per block);
//      two-phase sRed RMW reduce. 4 waves/SIMD, VALU floor 6.8 -> 3.8us.

#define NB 4
#define SEQ 512
#define HDIM 128
#define DDIM 256

static constexpr float TWO_LOG2E = 2.8853900817779268f; // 2*log2(e)
static constexpr float LOG2E     = 1.4426950408889634f;

// ---------------- Kernel W: transpose W1/W2 -> Wt[k][h] --------------------
// 16 blocks (2 W x 8 k-slices of 32 k) x 256 thr. Wt4[k*32 + hq] =
// {W[4hq+0][k], W[4hq+1][k], W[4hq+2][k], W[4hq+3][k]}.
__global__ __launch_bounds__(256) void wtrans_kernel(
    const float* __restrict__ W1, const float* __restrict__ W2,
    float* __restrict__ Wt1, float* __restrict__ Wt2)
{
    __shared__ float sT[32 * 132];   // [k_local][h], pad 132
    const int blk = blockIdx.x;
    const int which = blk >> 3;
    const int s = blk & 7;           // k-slice: k = s*32 + [0,32)
    const float* W  = which ? W2 : W1;
    float*       Wt = which ? Wt2 : Wt1;
    const int tid = threadIdx.x;

    #pragma unroll
    for (int i = 0; i < 4; ++i) {
        const int idx = i * 256 + tid;       // [0,1024)
        const int h = idx >> 3, k4 = idx & 7;
        const float4 v = ((const float4*)W)[h * 64 + s * 8 + k4];
        sT[(k4 * 4 + 0) * 132 + h] = v.x;
        sT[(k4 * 4 + 1) * 132 + h] = v.y;
        sT[(k4 * 4 + 2) * 132 + h] = v.z;
        sT[(k4 * 4 + 3) * 132 + h] = v.w;
    }
    __syncthreads();
    #pragma unroll
    for (int i = 0; i < 4; ++i) {
        const int idx = i * 256 + tid;       // [0,1024)
        const int kl = idx >> 5, hq = idx & 31;
        float4 o;
        o.x = sT[kl * 132 + 4 * hq + 0];
        o.y = sT[kl * 132 + 4 * hq + 1];
        o.z = sT[kl * 132 + 4 * hq + 2];
        o.w = sT[kl * 132 + 4 * hq + 3];
        ((float4*)Wt)[(s * 32 + kl) * 32 + hq] = o;
    }
}

// ---------------- Kernel A: fused projection + exp2 -----------------------
// 512 blocks x 256 thr. Block = 8 rows of x (gr0<2048) or y, full K=256.
// W read from TRANSPOSED Wt (coalesced: lanes hq consecutive float4).
// Epilogue applies exp2 and writes e1 swizzled / e2 linear directly.
__global__ __launch_bounds__(256) void proj_kernel(
    const float* __restrict__ x, const float* __restrict__ y,
    const float* __restrict__ Wt1, const float* __restrict__ Wt2,
    float* __restrict__ e1sw, float* __restrict__ e2)
{
    __shared__ float As[2048];      // [8 r][256 k]
    __shared__ float sPr[8192];     // [8 ks][8 r][128 h]
    const int tid = threadIdx.x;
    const int gr0 = blockIdx.x * 8;       // global virtual row base [0,4096)

    const float* in; const float* Wt; int srow;
    if (gr0 < 2048) { in = x; Wt = Wt1; srow = gr0; }
    else            { in = y; Wt = Wt2; srow = gr0 - 2048; }

    #pragma unroll
    for (int j = 0; j < 2; ++j) {
        const int idx = tid + j * 256;        // float4 slot [0,512)
        const int r = idx >> 6, kk = idx & 63;
        *(float4*)&As[idx * 4] =
            *(const float4*)&in[(srow + r) * 256 + kk * 4];
    }
    __syncthreads();

    const int hq = tid & 31;   // h-quad
    const int ks = tid >> 5;   // k-slice of 32
    const float4* Wt4 = (const float4*)Wt;

    float4 acc4[8];
    #pragma unroll
    for (int r = 0; r < 8; ++r) acc4[r] = make_float4(0.f, 0.f, 0.f, 0.f);

    #pragma unroll
    for (int u = 0; u < 8; ++u) {
        const int kof = ks * 32 + u * 4;
        // w_j = h-quad {4hq..4hq+3} at k = kof+j  (lane-consecutive float4s)
        const float4 w0 = Wt4[(kof + 0) * 32 + hq];
        const float4 w1 = Wt4[(kof + 1) * 32 + hq];
        const float4 w2 = Wt4[(kof + 2) * 32 + hq];
        const float4 w3 = Wt4[(kof + 3) * 32 + hq];
        #pragma unroll
        for (int r = 0; r < 8; ++r) {
            const float4 a = *(const float4*)&As[r * 256 + kof];
            acc4[r].x = fmaf(a.w,w3.x, fmaf(a.z,w2.x, fmaf(a.y,w1.x, fmaf(a.x,w0.x, acc4[r].x))));
            acc4[r].y = fmaf(a.w,w3.y, fmaf(a.z,w2.y, fmaf(a.y,w1.y, fmaf(a.x,w0.y, acc4[r].y))));
            acc4[r].z = fmaf(a.w,w3.z, fmaf(a.z,w2.z, fmaf(a.y,w1.z, fmaf(a.x,w0.z, acc4[r].z))));
            acc4[r].w = fmaf(a.w,w3.w, fmaf(a.z,w2.w, fmaf(a.y,w1.w, fmaf(a.x,w0.w, acc4[r].w))));
        }
    }
    #pragma unroll
    for (int r = 0; r < 8; ++r)
        *(float4*)&sPr[ks * 1024 + r * 128 + hq * 4] = acc4[r];
    __syncthreads();
    {
        const int r = tid >> 5, h4 = tid & 31;
        float4 s = make_float4(0.f, 0.f, 0.f, 0.f);
        #pragma unroll
        for (int k2 = 0; k2 < 8; ++k2) {
            const float4 p = *(const float4*)&sPr[k2 * 1024 + r * 128 + h4 * 4];
            s.x += p.x; s.y += p.y; s.z += p.z; s.w += p.w;
        }
        float4 o;
        o.x = __builtin_amdgcn_exp2f(s.x * TWO_LOG2E);
        o.y = __builtin_amdgcn_exp2f(s.y * TWO_LOG2E);
        o.z = __builtin_amdgcn_exp2f(s.z * TWO_LOG2E);
        o.w = __builtin_amdgcn_exp2f(s.w * TWO_LOG2E);
        const int gr = gr0 + r;
        if (gr < 2048) {
            const int b = gr >> 9, ss = gr & 511;
            const int c = ss >> 6, sl = ss & 63;
            ((float4*)e1sw)[((b * 8 + c) * 32 + h4) * 64 + (sl ^ h4)] = o;
        } else {
            ((float4*)e2)[(gr - 2048) * 32 + h4] = o;
        }
    }
}

// ---------------- Kernel B: scores + softmax -> P --------------------------
// 512 blocks x 1024 thr (16 waves). Block = (b, 4 t). Wave w = h-group of
// 8 h (quads 2w, 2w+1); each wave computes ALL 4 t per e1 value. e1 read
// direct from global (L2-resident) with DEPTH-1 PREFETCH (chunk c+1 loads
// issued before chunk c compute -> L2 latency hidden). Barrier cadence
// halved: 2 chunks per barrier, 2x2-buffered sPartC; 512-thread reduce of
// the pair overlaps with the other waves' next chunks. LDS 72 KB ->
// 2 blocks/CU = 32 waves/CU.
__global__ __launch_bounds__(1024) void score_kernel(
    const float* __restrict__ e1sw, const float* __restrict__ e2g,
    const float* __restrict__ vc,  float* __restrict__ P)
{
    __shared__ float sPartC[2][2][16 * 256];  // 64 KB: [pairbuf][c&1][w][t][64 s]
    __shared__ float sScore[4 * 512];         // 8 KB:  [t][512 s]

    const int tid  = threadIdx.x;
    const int b    = blockIdx.x >> 7;
    const int t0   = (blockIdx.x & 127) * 4;
    const int w    = tid >> 6;
    const int lane = tid & 63;
    const int wu   = __builtin_amdgcn_readfirstlane(w);
    const int hg   = wu;               // h-group: quads 2hg, 2hg+1

    // scalar operands: 2 vc quads + 4t x 2 e2 quads -> SGPRs
    float4 vcs[2];
    float4 e2s[4][2];
    #pragma unroll
    for (int j = 0; j < 2; ++j)
        vcs[j] = *(const float4*)&vc[(hg * 2 + j) * 4];
    #pragma unroll
    for (int t = 0; t < 4; ++t)
        #pragma unroll
        for (int j = 0; j < 2; ++j)
            e2s[t][j] = *(const float4*)&e2g[(b * SEQ + t0 + t) * HDIM + (hg * 2 + j) * 4];

    const float4* e1c = (const float4*)e1sw + b * 16384;  // 8 chunks x 2048

    // fixed per-lane offsets of the two h-quad loads within a chunk
    const int off0 = (hg * 2 + 0) * 64 + (lane ^ (hg * 2 + 0));
    const int off1 = (hg * 2 + 1) * 64 + (lane ^ (hg * 2 + 1));

    float4 e1v0 = e1c[off0];
    float4 e1v1 = e1c[off1];

    for (int c = 0; c < 8; ++c) {
        float4 e1n0 = e1v0, e1n1 = e1v1;
        if (c < 7) {
            const float4* nx = e1c + (c + 1) * 2048;
            e1n0 = nx[off0];
            e1n1 = nx[off1];
        }
        float acc0 = 0.f, acc1 = 0.f, acc2 = 0.f, acc3 = 0.f;
        #pragma unroll
        for (int j = 0; j < 2; ++j) {
            const float4 e1 = j ? e1v1 : e1v0;
            const float4 vv = vcs[j];
            #pragma unroll
            for (int t = 0; t < 4; ++t) {
                const float4 e2 = e2s[t][j];
                const float f1 = fmaf(e1.x, e2.x, 1.f);
                const float f2 = fmaf(e1.y, e2.y, 1.f);
                const float f3 = fmaf(e1.z, e2.z, 1.f);
                const float f4 = fmaf(e1.w, e2.w, 1.f);
                const float f12 = f1 * f2, f34 = f3 * f4;
                const float n12 = fmaf(vv.x, f2, vv.y * f1);
                const float n34 = fmaf(vv.z, f4, vv.w * f3);
                const float num = fmaf(n12, f34, n34 * f12);
                const float r = fmaf(num, __builtin_amdgcn_rcpf(f12 * f34),
                                     (t == 0) ? acc0 : (t == 1) ? acc1 : (t == 2) ? acc2 : acc3);
                if      (t == 0) acc0 = r;
                else if (t == 1) acc1 = r;
                else if (t == 2) acc2 = r;
                else             acc3 = r;
            }
        }
        float* pb = &sPartC[(c >> 1) & 1][c & 1][0] + wu * 256 + lane;
        pb[0 * 64] = acc0;
        pb[1 * 64] = acc1;
        pb[2 * 64] = acc2;
        pb[3 * 64] = acc3;
        if (c & 1) {
            __syncthreads();
            // reduce the pair (c-1, c); safe to overwrite this pairbuf only
            // after the NEXT barrier (iteration c+2), which reducers reach
            // only after finishing here.
            if (tid < 512) {
                const int ch = tid >> 8;             // chunk within pair
                const int t  = (tid >> 6) & 3, s = tid & 63;
                const float* pc = &sPartC[(c >> 1) & 1][ch][0] + t * 64 + s;
                float r = 0.f;
                #pragma unroll
                for (int ww = 0; ww < 16; ++ww) r += pc[ww * 256];
                sScore[t * 512 + (c - 1 + ch) * 64 + s] = -2.f * r;
            }
        }
        e1v0 = e1n0;
        e1v1 = e1n1;
    }
    __syncthreads();

    // softmax: waves 0..3 -> t0+w; write normalized P
    if (w < 4) {
        float v[8];
        float m = -1e30f;
        #pragma unroll
        for (int j = 0; j < 8; ++j) {
            v[j] = sScore[w * 512 + lane + j * 64];
            m = fmaxf(m, v[j]);
        }
        #pragma unroll
        for (int off = 32; off; off >>= 1) m = fmaxf(m, __shfl_xor(m, off));
        float sum = 0.f;
        #pragma unroll
        for (int j = 0; j < 8; ++j) {
            v[j] = __builtin_amdgcn_exp2f((v[j] - m) * LOG2E);
            sum += v[j];
        }
        #pragma unroll
        for (int off = 32; off; off >>= 1) sum += __shfl_xor(sum, off);
        const float inv = __builtin_amdgcn_rcpf(sum);
        float* Prow = &P[(b * SEQ + t0 + w) * SEQ];
        #pragma unroll
        for (int j = 0; j < 8; ++j)
            Prow[lane + j * 64] = v[j] * inv;
    }
}

// ---------------- Kernel C: out = P @ x ------------------------------------
// R14: 256 blocks x 1024 thr (16 waves, 4/SIMD). Wave w owns s-strip
// [32w, 32w+32) and ALL 8 t (x[b] read exactly once per block). Two-phase
// sRed reduce: waves 0-7 write, waves 8-15 RMW-add, then 8-way final.
// LDS 80 KB.
__global__ __launch_bounds__(1024) void pax_kernel(
    const float* __restrict__ P, const float* __restrict__ x,
    float* __restrict__ out)
{
    __shared__ float sP[SEQ * 8];        // 16 KB: [s][t]
    __shared__ float sRed[8 * 8 * DDIM]; // 64 KB: [q][t][d]
    const int tid = threadIdx.x;
    const int b   = blockIdx.x >> 6;
    const int t0  = (blockIdx.x & 63) * 8;
    const int w    = tid >> 6;
    const int lane = tid & 63;

    {
        const int t = tid >> 7, c4 = tid & 127;   // [0,1024)
        const float4 p = *(const float4*)&P[(b * SEQ + t0 + t) * SEQ + c4 * 4];
        sP[(c4 * 4 + 0) * 8 + t] = p.x;
        sP[(c4 * 4 + 1) * 8 + t] = p.y;
        sP[(c4 * 4 + 2) * 8 + t] = p.z;
        sP[(c4 * 4 + 3) * 8 + t] = p.w;
    }
    __syncthreads();

    const float4* x4 = (const float4*)x;
    float4 acc[8];
    #pragma unroll
    for (int t = 0; t < 8; ++t) acc[t] = make_float4(0.f, 0.f, 0.f, 0.f);

    #pragma unroll 4
    for (int si = 0; si < 32; ++si) {
        const int s = w * 32 + si;
        const float4 xv  = x4[(b * SEQ + s) * 64 + lane];
        const float4 p03 = *(const float4*)&sP[s * 8];
        const float4 p47 = *(const float4*)&sP[s * 8 + 4];
        acc[0].x = fmaf(p03.x, xv.x, acc[0].x); acc[0].y = fmaf(p03.x, xv.y, acc[0].y);
        acc[0].z = fmaf(p03.x, xv.z, acc[0].z); acc[0].w = fmaf(p03.x, xv.w, acc[0].w);
        acc[1].x = fmaf(p03.y, xv.x, acc[1].x); acc[1].y = fmaf(p03.y, xv.y, acc[1].y);
        acc[1].z = fmaf(p03.y, xv.z, acc[1].z); acc[1].w = fmaf(p03.y, xv.w, acc[1].w);
        acc[2].x = fmaf(p03.z, xv.x, acc[2].x); acc[2].y = fmaf(p03.z, xv.y, acc[2].y);
        acc[2].z = fmaf(p03.z, xv.z, acc[2].z); acc[2].w = fmaf(p03.z, xv.w, acc[2].w);
        acc[3].x = fmaf(p03.w, xv.x, acc[3].x); acc[3].y = fmaf(p03.w, xv.y, acc[3].y);
        acc[3].z = fmaf(p03.w, xv.z, acc[3].z); acc[3].w = fmaf(p03.w, xv.w, acc[3].w);
        acc[4].x = fmaf(p47.x, xv.x, acc[4].x); acc[4].y = fmaf(p47.x, xv.y, acc[4].y);
        acc[4].z = fmaf(p47.x, xv.z, acc[4].z); acc[4].w = fmaf(p47.x, xv.w, acc[4].w);
        acc[5].x = fmaf(p47.y, xv.x, acc[5].x); acc[5].y = fmaf(p47.y, xv.y, acc[5].y);
        acc[5].z = fmaf(p47.y, xv.z, acc[5].z); acc[5].w = fmaf(p47.y, xv.w, acc[5].w);
        acc[6].x = fmaf(p47.z, xv.x, acc[6].x); acc[6].y = fmaf(p47.z, xv.y, acc[6].y);
        acc[6].z = fmaf(p47.z, xv.z, acc[6].z); acc[6].w = fmaf(p47.z, xv.w, acc[6].w);
        acc[7].x = fmaf(p47.w, xv.x, acc[7].x); acc[7].y = fmaf(p47.w, xv.y, acc[7].y);
        acc[7].z = fmaf(p47.w, xv.z, acc[7].z); acc[7].w = fmaf(p47.w, xv.w, acc[7].w);
    }

    float4* sRed4 = (float4*)sRed;     // [8 q][8 t][64 lanes]
    if (w < 8) {
        #pragma unroll
        for (int t = 0; t < 8; ++t)
            sRed4[w * 512 + t * 64 + lane] = acc[t];
    }
    __syncthreads();
    if (w >= 8) {
        #pragma unroll
        for (int t = 0; t < 8; ++t) {
            float4 r = sRed4[(w - 8) * 512 + t * 64 + lane];
            r.x += acc[t].x; r.y += acc[t].y; r.z += acc[t].z; r.w += acc[t].w;
            sRed4[(w - 8) * 512 + t * 64 + lane] = r;
        }
    }
    __syncthreads();
    #pragma unroll
    for (int j = 0; j < 2; ++j) {
        const int i = tid + j * 1024;  // [0,2048): t = i>>8, d = i&255
        const int t = i >> 8, d = i & 255;
        float r = 0.f;
        #pragma unroll
        for (int q = 0; q < 8; ++q) r += sRed[q * 2048 + t * 256 + d];
        out[(b * SEQ + t0 + t) * DDIM + d] = r;
    }
}

extern "C" void kernel_launch(void* const* d_in, const int* in_sizes, int n_in,
                              void* d_out, int out_size, void* d_ws, size_t ws_size,
                              hipStream_t stream) {
    const float* x   = (const float*)d_in[0];   // (4,512,256)
    const float* y   = (const float*)d_in[1];   // (4,512,256)
    const float* W1  = (const float*)d_in[2];   // (128,256)
    const float* W2  = (const float*)d_in[3];   // (128,256)
    const float* vc  = (const float*)d_in[4];   // (1,128)
    float* outp = (float*)d_out;                // (4,512,256)

    float* ws  = (float*)d_ws;
    float* e1  = ws;                            // 1 MB (swizzled)
    float* e2  = ws + NB * SEQ * HDIM;          // 1 MB
    float* P   = ws + 2 * NB * SEQ * HDIM;      // 4 MB
    float* Wt1 = P + NB * SEQ * SEQ;            // 128 KB
    float* Wt2 = Wt1 + HDIM * DDIM;             // 128 KB

    hipLaunchKernelGGL(wtrans_kernel, dim3(16),  dim3(256),  0, stream,
                       W1, W2, Wt1, Wt2);
    hipLaunchKernelGGL(proj_kernel,   dim3(512), dim3(256),  0, stream,
                       x, y, Wt1, Wt2, e1, e2);
    hipLaunchKernelGGL(score_kernel,  dim3(512), dim3(1024), 0, stream,
                       e1, e2, vc, P);
    hipLaunchKernelGGL(pax_kernel,    dim3(256), dim3(1024), 0, stream,
                       P, x, outp);
}

// Round 5
// 95.915 us; speedup vs baseline: 1.9141x; 1.0215x over previous
//
#include <hip/hip_runtime.h>

// B=4, Sx=Sy=512, H=128, D=2H=256, fp32.
// e1 = exp2(2log2e * x@W1^T)  (stored PRE-SWIZZLED: [b][c][hq][s^hq] float4)
// e2 = exp2(2log2e * y@W2^T)  (linear)
// tanh(s1+s2) = 1 - 2/(e1*e2+1); score = sum_h vc[h]*tanh(.)
// constant sum_h vc[h] dropped (softmax shift-invariant); -2 folded into the
// chunk reduce. P = softmax_s(score); out = P @ x.
// Quad-rcp: v1/f1+..+v4/f4 = (n12*f34+n34*f12)/(f12*f34), one rcp per 4 h.
//
// R8: harness 256 MiB d_ws fill = ~40 us of every timed iteration (fixed tax).
// R11: FAILED: LDS float atomicAdd under 16-way collision -> score 96us.
// R12: score reads e1 direct from global; deterministic sPartC reduce.
// R13: wtrans pre-transposes W (proj W-loads were lane-scattered). 99.3us.
// R14: score prefetch + pax 1024thr -> only -1.3us (98.0). LESSON: kernel
//      times sum to ~17us; ~40us of the iteration is dispatch/gap overhead.
//      Intra-kernel tuning is exhausted; reduce the dispatch count.
// R15: score+pax FUSED (same (b,t-rows) decomposition): block = (b, 8t),
//      256 blk x 1024 thr. Reduce threads keep chunk sums in REGISTERS
//      (reducer(t,s) == softmax thread(t,s)) -> sScore LDS deleted; softmax
//      writes P into LDS sP; pax phase reads it (P never touches global).
//      Removes: 1 dispatch + gap, 8 MB P round-trip, pax P-load phase,
//      halves e1 L2 re-reads. LDS: one 64 KB arena, barrier-ordered reuse.

#define NB 4
#define SEQ 512
#define HDIM 128
#define DDIM 256

static constexpr float TWO_LOG2E = 2.8853900817779268f; // 2*log2(e)
static constexpr float LOG2E     = 1.4426950408889634f;

// ---------------- Kernel W: transpose W1/W2 -> Wt[k][h] --------------------
__global__ __launch_bounds__(256) void wtrans_kernel(
    const float* __restrict__ W1, const float* __restrict__ W2,
    float* __restrict__ Wt1, float* __restrict__ Wt2)
{
    __shared__ float sT[32 * 132];   // [k_local][h], pad 132
    const int blk = blockIdx.x;
    const int which = blk >> 3;
    const int s = blk & 7;           // k-slice: k = s*32 + [0,32)
    const float* W  = which ? W2 : W1;
    float*       Wt = which ? Wt2 : Wt1;
    const int tid = threadIdx.x;

    #pragma unroll
    for (int i = 0; i < 4; ++i) {
        const int idx = i * 256 + tid;       // [0,1024)
        const int h = idx >> 3, k4 = idx & 7;
        const float4 v = ((const float4*)W)[h * 64 + s * 8 + k4];
        sT[(k4 * 4 + 0) * 132 + h] = v.x;
        sT[(k4 * 4 + 1) * 132 + h] = v.y;
        sT[(k4 * 4 + 2) * 132 + h] = v.z;
        sT[(k4 * 4 + 3) * 132 + h] = v.w;
    }
    __syncthreads();
    #pragma unroll
    for (int i = 0; i < 4; ++i) {
        const int idx = i * 256 + tid;       // [0,1024)
        const int kl = idx >> 5, hq = idx & 31;
        float4 o;
        o.x = sT[kl * 132 + 4 * hq + 0];
        o.y = sT[kl * 132 + 4 * hq + 1];
        o.z = sT[kl * 132 + 4 * hq + 2];
        o.w = sT[kl * 132 + 4 * hq + 3];
        ((float4*)Wt)[(s * 32 + kl) * 32 + hq] = o;
    }
}

// ---------------- Kernel A: fused projection + exp2 -----------------------
// 512 blocks x 256 thr. Block = 8 rows of x (gr0<2048) or y, full K=256.
__global__ __launch_bounds__(256) void proj_kernel(
    const float* __restrict__ x, const float* __restrict__ y,
    const float* __restrict__ Wt1, const float* __restrict__ Wt2,
    float* __restrict__ e1sw, float* __restrict__ e2)
{
    __shared__ float As[2048];      // [8 r][256 k]
    __shared__ float sPr[8192];     // [8 ks][8 r][128 h]
    const int tid = threadIdx.x;
    const int gr0 = blockIdx.x * 8;       // global virtual row base [0,4096)

    const float* in; const float* Wt; int srow;
    if (gr0 < 2048) { in = x; Wt = Wt1; srow = gr0; }
    else            { in = y; Wt = Wt2; srow = gr0 - 2048; }

    #pragma unroll
    for (int j = 0; j < 2; ++j) {
        const int idx = tid + j * 256;        // float4 slot [0,512)
        const int r = idx >> 6, kk = idx & 63;
        *(float4*)&As[idx * 4] =
            *(const float4*)&in[(srow + r) * 256 + kk * 4];
    }
    __syncthreads();

    const int hq = tid & 31;   // h-quad
    const int ks = tid >> 5;   // k-slice of 32
    const float4* Wt4 = (const float4*)Wt;

    float4 acc4[8];
    #pragma unroll
    for (int r = 0; r < 8; ++r) acc4[r] = make_float4(0.f, 0.f, 0.f, 0.f);

    #pragma unroll
    for (int u = 0; u < 8; ++u) {
        const int kof = ks * 32 + u * 4;
        const float4 w0 = Wt4[(kof + 0) * 32 + hq];
        const float4 w1 = Wt4[(kof + 1) * 32 + hq];
        const float4 w2 = Wt4[(kof + 2) * 32 + hq];
        const float4 w3 = Wt4[(kof + 3) * 32 + hq];
        #pragma unroll
        for (int r = 0; r < 8; ++r) {
            const float4 a = *(const float4*)&As[r * 256 + kof];
            acc4[r].x = fmaf(a.w,w3.x, fmaf(a.z,w2.x, fmaf(a.y,w1.x, fmaf(a.x,w0.x, acc4[r].x))));
            acc4[r].y = fmaf(a.w,w3.y, fmaf(a.z,w2.y, fmaf(a.y,w1.y, fmaf(a.x,w0.y, acc4[r].y))));
            acc4[r].z = fmaf(a.w,w3.z, fmaf(a.z,w2.z, fmaf(a.y,w1.z, fmaf(a.x,w0.z, acc4[r].z))));
            acc4[r].w = fmaf(a.w,w3.w, fmaf(a.z,w2.w, fmaf(a.y,w1.w, fmaf(a.x,w0.w, acc4[r].w))));
        }
    }
    #pragma unroll
    for (int r = 0; r < 8; ++r)
        *(float4*)&sPr[ks * 1024 + r * 128 + hq * 4] = acc4[r];
    __syncthreads();
    {
        const int r = tid >> 5, h4 = tid & 31;
        float4 s = make_float4(0.f, 0.f, 0.f, 0.f);
        #pragma unroll
        for (int k2 = 0; k2 < 8; ++k2) {
            const float4 p = *(const float4*)&sPr[k2 * 1024 + r * 128 + h4 * 4];
            s.x += p.x; s.y += p.y; s.z += p.z; s.w += p.w;
        }
        float4 o;
        o.x = __builtin_amdgcn_exp2f(s.x * TWO_LOG2E);
        o.y = __builtin_amdgcn_exp2f(s.y * TWO_LOG2E);
        o.z = __builtin_amdgcn_exp2f(s.z * TWO_LOG2E);
        o.w = __builtin_amdgcn_exp2f(s.w * TWO_LOG2E);
        const int gr = gr0 + r;
        if (gr < 2048) {
            const int b = gr >> 9, ss = gr & 511;
            const int c = ss >> 6, sl = ss & 63;
            ((float4*)e1sw)[((b * 8 + c) * 32 + h4) * 64 + (sl ^ h4)] = o;
        } else {
            ((float4*)e2)[(gr - 2048) * 32 + h4] = o;
        }
    }
}

// ---------------- Kernel B: fused scores + softmax + P@x -------------------
// 256 blocks x 1024 thr (16 waves). Block = (b, 8 t-rows). Phase 1: wave w
// = h-group hg (quads 2hg,2hg+1) computes partial scores for ALL 8 t per e1
// value (e1 direct from global, depth-1 prefetch). Per chunk: partials ->
// sPartC[c&1], barrier, threads tid<512 (= (t,s) owners) accumulate the
// 16-wave sum into REGISTERS v[c]. After 8 chunks the same threads run the
// softmax on v[] and write normalized P into LDS sP[s][t]. Phase 2: pax --
// wave w owns s-strip [32w,32w+32) and all 8 t, reads sP/x, two-phase sRed
// reduce, write out. P never touches global. LDS: one 64 KB arena
// (sPartC dbuf -> sP -> sRed), barrier-ordered reuse.
__global__ __launch_bounds__(1024) void score_pax_kernel(
    const float* __restrict__ e1sw, const float* __restrict__ e2g,
    const float* __restrict__ vc,  const float* __restrict__ x,
    float* __restrict__ out)
{
    __shared__ float sBig[16384];   // 64 KB arena

    const int tid  = threadIdx.x;
    const int b    = blockIdx.x >> 6;
    const int t0   = (blockIdx.x & 63) * 8;
    const int w    = tid >> 6;
    const int lane = tid & 63;
    const int wu   = __builtin_amdgcn_readfirstlane(w);
    const int hg   = wu;               // h-group: quads 2hg, 2hg+1

    // scalar operands: 2 vc quads + 8t x 2 e2 quads (wave-uniform addrs)
    float4 vcs[2];
    float4 e2s[8][2];
    #pragma unroll
    for (int j = 0; j < 2; ++j)
        vcs[j] = *(const float4*)&vc[(hg * 2 + j) * 4];
    #pragma unroll
    for (int t = 0; t < 8; ++t)
        #pragma unroll
        for (int j = 0; j < 2; ++j)
            e2s[t][j] = *(const float4*)&e2g[(b * SEQ + t0 + t) * HDIM + (hg * 2 + j) * 4];

    const float4* e1c = (const float4*)e1sw + b * 16384;  // 8 chunks x 2048

    // fixed per-lane offsets of the two h-quad loads within a chunk
    const int off0 = (hg * 2 + 0) * 64 + (lane ^ (hg * 2 + 0));
    const int off1 = (hg * 2 + 1) * 64 + (lane ^ (hg * 2 + 1));

    float4 e1v0 = e1c[off0];
    float4 e1v1 = e1c[off1];

    float v[8];   // reducer/softmax registers: v[c] = score(t=tid>>6, s=c*64+lane)

    for (int c = 0; c < 8; ++c) {
        float4 e1n0 = e1v0, e1n1 = e1v1;
        if (c < 7) {
            const float4* nx = e1c + (c + 1) * 2048;
            e1n0 = nx[off0];
            e1n1 = nx[off1];
        }
        float acc[8];
        #pragma unroll
        for (int t = 0; t < 8; ++t) acc[t] = 0.f;
        #pragma unroll
        for (int j = 0; j < 2; ++j) {
            const float4 e1 = j ? e1v1 : e1v0;
            const float4 vv = vcs[j];
            #pragma unroll
            for (int t = 0; t < 8; ++t) {
                const float4 e2 = e2s[t][j];
                const float f1 = fmaf(e1.x, e2.x, 1.f);
                const float f2 = fmaf(e1.y, e2.y, 1.f);
                const float f3 = fmaf(e1.z, e2.z, 1.f);
                const float f4 = fmaf(e1.w, e2.w, 1.f);
                const float f12 = f1 * f2, f34 = f3 * f4;
                const float n12 = fmaf(vv.x, f2, vv.y * f1);
                const float n34 = fmaf(vv.z, f4, vv.w * f3);
                const float num = fmaf(n12, f34, n34 * f12);
                acc[t] = fmaf(num, __builtin_amdgcn_rcpf(f12 * f34), acc[t]);
            }
        }
        // partials: sPartC[c&1][w][t][64 s]
        float* pb = sBig + (c & 1) * 8192 + wu * 512 + lane;
        #pragma unroll
        for (int t = 0; t < 8; ++t) pb[t * 64] = acc[t];
        __syncthreads();
        if (tid < 512) {
            const int t = tid >> 6, s = tid & 63;
            const float* pc = sBig + (c & 1) * 8192 + t * 64 + s;
            float r = 0.f;
            #pragma unroll
            for (int ww = 0; ww < 16; ++ww) r += pc[ww * 512];
            v[c] = -2.f * r;
        }
        e1v0 = e1n0;
        e1v1 = e1n1;
    }

    // softmax by tid<512 (thread (t,s) holds v[c] = score(t, c*64+s));
    // write normalized P into sP[s][t] = sBig[s*8+t]. sBig buf-0 region is
    // last read at chunk-6 reduce; chunk-7 reduce reads buf 1 -> safe.
    if (tid < 512) {
        const int t = w;  // tid>>6
        float m = -1e30f;
        #pragma unroll
        for (int j = 0; j < 8; ++j) m = fmaxf(m, v[j]);
        #pragma unroll
        for (int off = 32; off; off >>= 1) m = fmaxf(m, __shfl_xor(m, off));
        float sum = 0.f;
        #pragma unroll
        for (int j = 0; j < 8; ++j) {
            v[j] = __builtin_amdgcn_exp2f((v[j] - m) * LOG2E);
            sum += v[j];
        }
        #pragma unroll
        for (int off = 32; off; off >>= 1) sum += __shfl_xor(sum, off);
        const float inv = __builtin_amdgcn_rcpf(sum);
        #pragma unroll
        for (int j = 0; j < 8; ++j)
            sBig[(j * 64 + lane) * 8 + t] = v[j] * inv;
    }
    __syncthreads();

    // ---- pax phase: wave w owns s-strip [32w, 32w+32), all 8 t ----
    const float4* x4 = (const float4*)x;
    float4 acc[8];
    #pragma unroll
    for (int t = 0; t < 8; ++t) acc[t] = make_float4(0.f, 0.f, 0.f, 0.f);

    #pragma unroll 4
    for (int si = 0; si < 32; ++si) {
        const int s = w * 32 + si;
        const float4 xv  = x4[(b * SEQ + s) * 64 + lane];
        const float4 p03 = *(const float4*)&sBig[s * 8];
        const float4 p47 = *(const float4*)&sBig[s * 8 + 4];
        acc[0].x = fmaf(p03.x, xv.x, acc[0].x); acc[0].y = fmaf(p03.x, xv.y, acc[0].y);
        acc[0].z = fmaf(p03.x, xv.z, acc[0].z); acc[0].w = fmaf(p03.x, xv.w, acc[0].w);
        acc[1].x = fmaf(p03.y, xv.x, acc[1].x); acc[1].y = fmaf(p03.y, xv.y, acc[1].y);
        acc[1].z = fmaf(p03.y, xv.z, acc[1].z); acc[1].w = fmaf(p03.y, xv.w, acc[1].w);
        acc[2].x = fmaf(p03.z, xv.x, acc[2].x); acc[2].y = fmaf(p03.z, xv.y, acc[2].y);
        acc[2].z = fmaf(p03.z, xv.z, acc[2].z); acc[2].w = fmaf(p03.z, xv.w, acc[2].w);
        acc[3].x = fmaf(p03.w, xv.x, acc[3].x); acc[3].y = fmaf(p03.w, xv.y, acc[3].y);
        acc[3].z = fmaf(p03.w, xv.z, acc[3].z); acc[3].w = fmaf(p03.w, xv.w, acc[3].w);
        acc[4].x = fmaf(p47.x, xv.x, acc[4].x); acc[4].y = fmaf(p47.x, xv.y, acc[4].y);
        acc[4].z = fmaf(p47.x, xv.z, acc[4].z); acc[4].w = fmaf(p47.x, xv.w, acc[4].w);
        acc[5].x = fmaf(p47.y, xv.x, acc[5].x); acc[5].y = fmaf(p47.y, xv.y, acc[5].y);
        acc[5].z = fmaf(p47.y, xv.z, acc[5].z); acc[5].w = fmaf(p47.y, xv.w, acc[5].w);
        acc[6].x = fmaf(p47.z, xv.x, acc[6].x); acc[6].y = fmaf(p47.z, xv.y, acc[6].y);
        acc[6].z = fmaf(p47.z, xv.z, acc[6].z); acc[6].w = fmaf(p47.z, xv.w, acc[6].w);
        acc[7].x = fmaf(p47.w, xv.x, acc[7].x); acc[7].y = fmaf(p47.w, xv.y, acc[7].y);
        acc[7].z = fmaf(p47.w, xv.z, acc[7].z); acc[7].w = fmaf(p47.w, xv.w, acc[7].w);
    }
    __syncthreads();   // sP fully consumed; sBig may be clobbered as sRed

    float4* sRed4 = (float4*)sBig;     // [8 q][8 t][64 lanes]
    if (w < 8) {
        #pragma unroll
        for (int t = 0; t < 8; ++t)
            sRed4[w * 512 + t * 64 + lane] = acc[t];
    }
    __syncthreads();
    if (w >= 8) {
        #pragma unroll
        for (int t = 0; t < 8; ++t) {
            float4 r = sRed4[(w - 8) * 512 + t * 64 + lane];
            r.x += acc[t].x; r.y += acc[t].y; r.z += acc[t].z; r.w += acc[t].w;
            sRed4[(w - 8) * 512 + t * 64 + lane] = r;
        }
    }
    __syncthreads();
    #pragma unroll
    for (int j = 0; j < 2; ++j) {
        const int i = tid + j * 1024;  // [0,2048): t = i>>8, d = i&255
        const int t = i >> 8, d = i & 255;
        float r = 0.f;
        #pragma unroll
        for (int q = 0; q < 8; ++q) r += sBig[q * 2048 + t * 256 + d];
        out[(b * SEQ + t0 + t) * DDIM + d] = r;
    }
}

extern "C" void kernel_launch(void* const* d_in, const int* in_sizes, int n_in,
                              void* d_out, int out_size, void* d_ws, size_t ws_size,
                              hipStream_t stream) {
    const float* x   = (const float*)d_in[0];   // (4,512,256)
    const float* y   = (const float*)d_in[1];   // (4,512,256)
    const float* W1  = (const float*)d_in[2];   // (128,256)
    const float* W2  = (const float*)d_in[3];   // (128,256)
    const float* vc  = (const float*)d_in[4];   // (1,128)
    float* outp = (float*)d_out;                // (4,512,256)

    float* ws  = (float*)d_ws;
    float* e1  = ws;                            // 1 MB (swizzled)
    float* e2  = ws + NB * SEQ * HDIM;          // 1 MB
    float* Wt1 = ws + 2 * NB * SEQ * HDIM;      // 128 KB
    float* Wt2 = Wt1 + HDIM * DDIM;             // 128 KB

    hipLaunchKernelGGL(wtrans_kernel,    dim3(16),  dim3(256),  0, stream,
                       W1, W2, Wt1, Wt2);
    hipLaunchKernelGGL(proj_kernel,      dim3(512), dim3(256),  0, stream,
                       x, y, Wt1, Wt2, e1, e2);
    hipLaunchKernelGGL(score_pax_kernel, dim3(256), dim3(1024), 0, stream,
                       e1, e2, vc, x, outp);
}

// Round 7
// 91.951 us; speedup vs baseline: 1.9967x; 1.0431x over previous
//
#include <hip/hip_runtime.h>

// B=4, Sx=Sy=512, H=128, D=2H=256, fp32.
// e1 = exp2(2log2e * x@W1^T)  (stored PRE-SWIZZLED: [b][c][hq][s^hq] float4)
// e2 = exp2(2log2e * y@W2^T)  (linear)
// tanh(s1+s2) = 1 - 2/(e1*e2+1); score = sum_h vc[h]*tanh(.)
// constant sum_h vc[h] dropped (softmax shift-invariant); -2 folded into the
// chunk reduce. P = softmax_s(score); out = P @ x.
// Quad-rcp: v1/f1+..+v4/f4 = (n12*f34+n34*f12)/(f12*f34), one rcp per 4 h.
//
// R8:  harness 256 MiB d_ws fill = ~40 us fixed tax per timed iteration.
// R11: FAILED: LDS float atomicAdd under 16-way collision.
// R12: e1 direct from global (no intra-block reuse in G=16 layout).
// R13: wtrans pre-transpose fixed proj W-load scatter. 99.3us.
// R14: prefetch/occupancy tuning: -1.3us. R15: score+pax fused: -2.1us
//      (95.9). LESSON: dispatch boundary ~1-2us each.
// R16: FAILED (container hang x2): cooperative grid.sync likely not
//      preserved through hipGraph capture/replay -> infinite spin. Never
//      retry cooperative launch in this harness.
// R17: wtrans DELETED without losing coalescing: proj threads take an
//      INTERLEAVED k-footprint (thread (hq,ks) covers k-float4 {u*8+ks}),
//      so wave lanes (ks minor) read consecutive float4s along k of the
//      ORIGINAL W[h][k] layout (8x128B segments/wave-load, = Wt quality).
//      Cross-ks sPr reduce unchanged. 2 dispatches total; score_pax is
//      byte-identical to R15 for attribution.

#define NB 4
#define SEQ 512
#define HDIM 128
#define DDIM 256

static constexpr float TWO_LOG2E = 2.8853900817779268f; // 2*log2(e)
static constexpr float LOG2E     = 1.4426950408889634f;

// ---------------- Kernel A: fused projection + exp2 -----------------------
// 512 blocks x 256 thr. Block = 8 rows of x (gr0<2048) or y, full K=256.
// Thread (hq = tid>>3, ks = tid&7); k-footprint interleaved: float4 index
// kf = u*8 + ks. W loads coalesce in the ORIGINAL [h][k] layout.
// Epilogue applies exp2 and writes e1 swizzled / e2 linear directly.
__global__ __launch_bounds__(256) void proj_kernel(
    const float* __restrict__ x, const float* __restrict__ y,
    const float* __restrict__ W1, const float* __restrict__ W2,
    float* __restrict__ e1sw, float* __restrict__ e2)
{
    __shared__ float As[2048];      // [8 r][256 k]
    __shared__ float sPr[8192];     // [8 ks][8 r][128 h]
    const int tid = threadIdx.x;
    const int gr0 = blockIdx.x * 8;       // global virtual row base [0,4096)

    const float* in; const float* W; int srow;
    if (gr0 < 2048) { in = x; W = W1; srow = gr0; }
    else            { in = y; W = W2; srow = gr0 - 2048; }

    #pragma unroll
    for (int j = 0; j < 2; ++j) {
        const int idx = tid + j * 256;        // float4 slot [0,512)
        const int r = idx >> 6, kk = idx & 63;
        *(float4*)&As[idx * 4] =
            *(const float4*)&in[(srow + r) * 256 + kk * 4];
    }
    __syncthreads();

    const int hq = tid >> 3;   // h-quad [0,32)
    const int ks = tid & 7;    // k-interleave slot [0,8)
    const float4* W4  = (const float4*)W;    // row stride 64 float4
    const float4* As4 = (const float4*)As;   // row stride 64 float4

    float4 acc4[8];
    #pragma unroll
    for (int r = 0; r < 8; ++r) acc4[r] = make_float4(0.f, 0.f, 0.f, 0.f);

    #pragma unroll
    for (int u = 0; u < 8; ++u) {
        const int kf = u * 8 + ks;           // interleaved k-float4 index
        // lanes (ks minor) -> consecutive float4s of each W row: coalesced
        const float4 w0 = W4[(4 * hq + 0) * 64 + kf];
        const float4 w1 = W4[(4 * hq + 1) * 64 + kf];
        const float4 w2 = W4[(4 * hq + 2) * 64 + kf];
        const float4 w3 = W4[(4 * hq + 3) * 64 + kf];
        #pragma unroll
        for (int r = 0; r < 8; ++r) {
            const float4 a = As4[r * 64 + kf];
            acc4[r].x = fmaf(a.w,w0.w, fmaf(a.z,w0.z, fmaf(a.y,w0.y, fmaf(a.x,w0.x, acc4[r].x))));
            acc4[r].y = fmaf(a.w,w1.w, fmaf(a.z,w1.z, fmaf(a.y,w1.y, fmaf(a.x,w1.x, acc4[r].y))));
            acc4[r].z = fmaf(a.w,w2.w, fmaf(a.z,w2.z, fmaf(a.y,w2.y, fmaf(a.x,w2.x, acc4[r].z))));
            acc4[r].w = fmaf(a.w,w3.w, fmaf(a.z,w3.z, fmaf(a.y,w3.y, fmaf(a.x,w3.x, acc4[r].w))));
        }
    }
    #pragma unroll
    for (int r = 0; r < 8; ++r)
        *(float4*)&sPr[ks * 1024 + r * 128 + hq * 4] = acc4[r];
    __syncthreads();
    {
        const int r = tid >> 5, h4 = tid & 31;
        float4 s = make_float4(0.f, 0.f, 0.f, 0.f);
        #pragma unroll
        for (int k2 = 0; k2 < 8; ++k2) {
            const float4 p = *(const float4*)&sPr[k2 * 1024 + r * 128 + h4 * 4];
            s.x += p.x; s.y += p.y; s.z += p.z; s.w += p.w;
        }
        float4 o;
        o.x = __builtin_amdgcn_exp2f(s.x * TWO_LOG2E);
        o.y = __builtin_amdgcn_exp2f(s.y * TWO_LOG2E);
        o.z = __builtin_amdgcn_exp2f(s.z * TWO_LOG2E);
        o.w = __builtin_amdgcn_exp2f(s.w * TWO_LOG2E);
        const int gr = gr0 + r;
        if (gr < 2048) {
            const int b = gr >> 9, ss = gr & 511;
            const int c = ss >> 6, sl = ss & 63;
            ((float4*)e1sw)[((b * 8 + c) * 32 + h4) * 64 + (sl ^ h4)] = o;
        } else {
            ((float4*)e2)[(gr - 2048) * 32 + h4] = o;
        }
    }
}

// ---------------- Kernel B: fused scores + softmax + P@x -------------------
// (byte-identical to R15) 256 blocks x 1024 thr (16 waves). Block =
// (b, 8 t-rows). Phase 1: wave w = h-group hg computes partial scores for
// ALL 8 t per e1 value (e1 direct from global, depth-1 prefetch). Per
// chunk: partials -> sPartC[c&1], barrier, tid<512 accumulate the 16-wave
// sum into registers v[c]. Then softmax on v[], normalized P into LDS
// sP[s][t]. Phase 2: pax; P never touches global. LDS: 64 KB arena.
__global__ __launch_bounds__(1024) void score_pax_kernel(
    const float* __restrict__ e1sw, const float* __restrict__ e2g,
    const float* __restrict__ vc,  const float* __restrict__ x,
    float* __restrict__ out)
{
    __shared__ float sBig[16384];   // 64 KB arena

    const int tid  = threadIdx.x;
    const int b    = blockIdx.x >> 6;
    const int t0   = (blockIdx.x & 63) * 8;
    const int w    = tid >> 6;
    const int lane = tid & 63;
    const int wu   = __builtin_amdgcn_readfirstlane(w);
    const int hg   = wu;               // h-group: quads 2hg, 2hg+1

    // scalar operands: 2 vc quads + 8t x 2 e2 quads (wave-uniform addrs)
    float4 vcs[2];
    float4 e2s[8][2];
    #pragma unroll
    for (int j = 0; j < 2; ++j)
        vcs[j] = *(const float4*)&vc[(hg * 2 + j) * 4];
    #pragma unroll
    for (int t = 0; t < 8; ++t)
        #pragma unroll
        for (int j = 0; j < 2; ++j)
            e2s[t][j] = *(const float4*)&e2g[(b * SEQ + t0 + t) * HDIM + (hg * 2 + j) * 4];

    const float4* e1c = (const float4*)e1sw + b * 16384;  // 8 chunks x 2048

    // fixed per-lane offsets of the two h-quad loads within a chunk
    const int off0 = (hg * 2 + 0) * 64 + (lane ^ (hg * 2 + 0));
    const int off1 = (hg * 2 + 1) * 64 + (lane ^ (hg * 2 + 1));

    float4 e1v0 = e1c[off0];
    float4 e1v1 = e1c[off1];

    float v[8];   // v[c] = score(t = tid>>6, s = c*64 + lane) for tid<512

    for (int c = 0; c < 8; ++c) {
        float4 e1n0 = e1v0, e1n1 = e1v1;
        if (c < 7) {
            const float4* nx = e1c + (c + 1) * 2048;
            e1n0 = nx[off0];
            e1n1 = nx[off1];
        }
        float acc[8];
        #pragma unroll
        for (int t = 0; t < 8; ++t) acc[t] = 0.f;
        #pragma unroll
        for (int j = 0; j < 2; ++j) {
            const float4 e1 = j ? e1v1 : e1v0;
            const float4 vv = vcs[j];
            #pragma unroll
            for (int t = 0; t < 8; ++t) {
                const float4 e2 = e2s[t][j];
                const float f1 = fmaf(e1.x, e2.x, 1.f);
                const float f2 = fmaf(e1.y, e2.y, 1.f);
                const float f3 = fmaf(e1.z, e2.z, 1.f);
                const float f4 = fmaf(e1.w, e2.w, 1.f);
                const float f12 = f1 * f2, f34 = f3 * f4;
                const float n12 = fmaf(vv.x, f2, vv.y * f1);
                const float n34 = fmaf(vv.z, f4, vv.w * f3);
                const float num = fmaf(n12, f34, n34 * f12);
                acc[t] = fmaf(num, __builtin_amdgcn_rcpf(f12 * f34), acc[t]);
            }
        }
        // partials: sPartC[c&1][w][t][64 s]
        float* pb = sBig + (c & 1) * 8192 + wu * 512 + lane;
        #pragma unroll
        for (int t = 0; t < 8; ++t) pb[t * 64] = acc[t];
        __syncthreads();
        if (tid < 512) {
            const int t = tid >> 6, s = tid & 63;
            const float* pc = sBig + (c & 1) * 8192 + t * 64 + s;
            float r = 0.f;
            #pragma unroll
            for (int ww = 0; ww < 16; ++ww) r += pc[ww * 512];
            v[c] = -2.f * r;
        }
        e1v0 = e1n0;
        e1v1 = e1n1;
    }

    // softmax by tid<512 (thread (t,s) holds v[c] = score(t, c*64+s));
    // write normalized P into sP[s][t] = sBig[s*8+t]. sBig buf-0 region is
    // last read at chunk-6 reduce; chunk-7 reduce reads buf 1 -> safe.
    if (tid < 512) {
        const int t = w;  // tid>>6
        float m = -1e30f;
        #pragma unroll
        for (int j = 0; j < 8; ++j) m = fmaxf(m, v[j]);
        #pragma unroll
        for (int off = 32; off; off >>= 1) m = fmaxf(m, __shfl_xor(m, off));
        float sum = 0.f;
        #pragma unroll
        for (int j = 0; j < 8; ++j) {
            v[j] = __builtin_amdgcn_exp2f((v[j] - m) * LOG2E);
            sum += v[j];
        }
        #pragma unroll
        for (int off = 32; off; off >>= 1) sum += __shfl_xor(sum, off);
        const float inv = __builtin_amdgcn_rcpf(sum);
        #pragma unroll
        for (int j = 0; j < 8; ++j)
            sBig[(j * 64 + lane) * 8 + t] = v[j] * inv;
    }
    __syncthreads();

    // ---- pax: wave w owns s-strip [32w, 32w+32), all 8 t ----
    const float4* x4 = (const float4*)x;
    float4 acc[8];
    #pragma unroll
    for (int t = 0; t < 8; ++t) acc[t] = make_float4(0.f, 0.f, 0.f, 0.f);

    #pragma unroll 4
    for (int si = 0; si < 32; ++si) {
        const int s = w * 32 + si;
        const float4 xv  = x4[(b * SEQ + s) * 64 + lane];
        const float4 p03 = *(const float4*)&sBig[s * 8];
        const float4 p47 = *(const float4*)&sBig[s * 8 + 4];
        acc[0].x = fmaf(p03.x, xv.x, acc[0].x); acc[0].y = fmaf(p03.x, xv.y, acc[0].y);
        acc[0].z = fmaf(p03.x, xv.z, acc[0].z); acc[0].w = fmaf(p03.x, xv.w, acc[0].w);
        acc[1].x = fmaf(p03.y, xv.x, acc[1].x); acc[1].y = fmaf(p03.y, xv.y, acc[1].y);
        acc[1].z = fmaf(p03.y, xv.z, acc[1].z); acc[1].w = fmaf(p03.y, xv.w, acc[1].w);
        acc[2].x = fmaf(p03.z, xv.x, acc[2].x); acc[2].y = fmaf(p03.z, xv.y, acc[2].y);
        acc[2].z = fmaf(p03.z, xv.z, acc[2].z); acc[2].w = fmaf(p03.z, xv.w, acc[2].w);
        acc[3].x = fmaf(p03.w, xv.x, acc[3].x); acc[3].y = fmaf(p03.w, xv.y, acc[3].y);
        acc[3].z = fmaf(p03.w, xv.z, acc[3].z); acc[3].w = fmaf(p03.w, xv.w, acc[3].w);
        acc[4].x = fmaf(p47.x, xv.x, acc[4].x); acc[4].y = fmaf(p47.x, xv.y, acc[4].y);
        acc[4].z = fmaf(p47.x, xv.z, acc[4].z); acc[4].w = fmaf(p47.x, xv.w, acc[4].w);
        acc[5].x = fmaf(p47.y, xv.x, acc[5].x); acc[5].y = fmaf(p47.y, xv.y, acc[5].y);
        acc[5].z = fmaf(p47.y, xv.z, acc[5].z); acc[5].w = fmaf(p47.y, xv.w, acc[5].w);
        acc[6].x = fmaf(p47.z, xv.x, acc[6].x); acc[6].y = fmaf(p47.z, xv.y, acc[6].y);
        acc[6].z = fmaf(p47.z, xv.z, acc[6].z); acc[6].w = fmaf(p47.z, xv.w, acc[6].w);
        acc[7].x = fmaf(p47.w, xv.x, acc[7].x); acc[7].y = fmaf(p47.w, xv.y, acc[7].y);
        acc[7].z = fmaf(p47.w, xv.z, acc[7].z); acc[7].w = fmaf(p47.w, xv.w, acc[7].w);
    }
    __syncthreads();   // sP fully consumed; sBig reused as sRed

    float4* sRed4 = (float4*)sBig;     // [8 q][8 t][64 lanes]
    if (w < 8) {
        #pragma unroll
        for (int t = 0; t < 8; ++t)
            sRed4[w * 512 + t * 64 + lane] = acc[t];
    }
    __syncthreads();
    if (w >= 8) {
        #pragma unroll
        for (int t = 0; t < 8; ++t) {
            float4 r = sRed4[(w - 8) * 512 + t * 64 + lane];
            r.x += acc[t].x; r.y += acc[t].y; r.z += acc[t].z; r.w += acc[t].w;
            sRed4[(w - 8) * 512 + t * 64 + lane] = r;
        }
    }
    __syncthreads();
    #pragma unroll
    for (int j = 0; j < 2; ++j) {
        const int i = tid + j * 1024;  // [0,2048): t = i>>8, d = i&255
        const int t = i >> 8, d = i & 255;
        float r = 0.f;
        #pragma unroll
        for (int q = 0; q < 8; ++q) r += sBig[q * 2048 + t * 256 + d];
        out[(b * SEQ + t0 + t) * DDIM + d] = r;
    }
}

extern "C" void kernel_launch(void* const* d_in, const int* in_sizes, int n_in,
                              void* d_out, int out_size, void* d_ws, size_t ws_size,
                              hipStream_t stream) {
    const float* x   = (const float*)d_in[0];   // (4,512,256)
    const float* y   = (const float*)d_in[1];   // (4,512,256)
    const float* W1  = (const float*)d_in[2];   // (128,256)
    const float* W2  = (const float*)d_in[3];   // (128,256)
    const float* vc  = (const float*)d_in[4];   // (1,128)
    float* outp = (float*)d_out;                // (4,512,256)

    float* ws = (float*)d_ws;
    float* e1 = ws;                             // 1 MB (swizzled)
    float* e2 = ws + NB * SEQ * HDIM;           // 1 MB

    hipLaunchKernelGGL(proj_kernel,      dim3(512), dim3(256),  0, stream,
                       x, y, W1, W2, e1, e2);
    hipLaunchKernelGGL(score_pax_kernel, dim3(256), dim3(1024), 0, stream,
                       e1, e2, vc, x, outp);
}